// Round 1
// baseline (990.595 us; speedup 1.0000x reference)
//
#include <hip/hip_runtime.h>
#include <math.h>

// Problem constants (B,S,D,H from reference)
constexpr int Bb = 2, Ss = 2048, Dd = 1024, Hh = 16, HDd = 64;

// ---------------------------------------------------------------------------
// fp32 tiled GEMM: C[M][N] = A[M][K] @ B[K][N] + bias[N]
// BM=BN=128, BK=16, 256 threads, 8x8 per thread.
// ---------------------------------------------------------------------------
template<int BM, int BN, int BK, int TM, int TN>
__global__ __launch_bounds__(256) void gemm_bias_f32(
    const float* __restrict__ A, const float* __restrict__ Bm,
    const float* __restrict__ bias, float* __restrict__ C,
    int M, int N, int K)
{
  __shared__ float As[BK][BM + 4];   // A stored transposed: As[k][m]
  __shared__ float Bs[BK][BN + 4];   // Bs[k][n]
  const int tid = threadIdx.x;
  const int ty = tid >> 4, tx = tid & 15;     // 16x16 thread grid
  const int m0 = blockIdx.y * BM, n0 = blockIdx.x * BN;

  float acc[TM][TN];
  #pragma unroll
  for (int i = 0; i < TM; i++)
    #pragma unroll
    for (int j = 0; j < TN; j++) acc[i][j] = 0.f;

  for (int k0 = 0; k0 < K; k0 += BK) {
    // stage A tile (BM x BK), transposed into LDS
    #pragma unroll
    for (int rep = 0; rep < (BM * BK) / (256 * 4); ++rep) {
      int f = tid + rep * 256;                 // float4 id
      int row = f / (BK / 4);
      int c4  = (f % (BK / 4)) * 4;
      float4 a = *(const float4*)(A + (size_t)(m0 + row) * K + k0 + c4);
      As[c4 + 0][row] = a.x; As[c4 + 1][row] = a.y;
      As[c4 + 2][row] = a.z; As[c4 + 3][row] = a.w;
    }
    // stage B tile (BK x BN)
    #pragma unroll
    for (int rep = 0; rep < (BK * BN) / (256 * 4); ++rep) {
      int f = tid + rep * 256;
      int row = f / (BN / 4);
      int c4  = (f % (BN / 4)) * 4;
      *(float4*)&Bs[row][c4] = *(const float4*)(Bm + (size_t)(k0 + row) * N + n0 + c4);
    }
    __syncthreads();

    #pragma unroll
    for (int kk = 0; kk < BK; ++kk) {
      float ra[TM], rb[TN];
      #pragma unroll
      for (int i = 0; i < TM; i += 4)
        *(float4*)&ra[i] = *(float4*)&As[kk][ty * TM + i];
      #pragma unroll
      for (int j = 0; j < TN; j += 4)
        *(float4*)&rb[j] = *(float4*)&Bs[kk][tx * TN + j];
      #pragma unroll
      for (int i = 0; i < TM; i++)
        #pragma unroll
        for (int j = 0; j < TN; j++)
          acc[i][j] += ra[i] * rb[j];
    }
    __syncthreads();
  }

  // epilogue: add bias, store
  #pragma unroll
  for (int i = 0; i < TM; i++) {
    int row = m0 + ty * TM + i;
    #pragma unroll
    for (int j = 0; j < TN; j += 4) {
      int col = n0 + tx * TN + j;
      float4 o;
      o.x = acc[i][j + 0] + bias[col + 0];
      o.y = acc[i][j + 1] + bias[col + 1];
      o.z = acc[i][j + 2] + bias[col + 2];
      o.w = acc[i][j + 3] + bias[col + 3];
      *(float4*)(C + (size_t)row * N + col) = o;
    }
  }
}

// ---------------------------------------------------------------------------
// Flash attention fp32. qkv layout: [B*S][H*3*HD] (per-head interleaved q,k,v).
// One block per (b, h, 64-row q-tile). Causal. Output att: [B*S][D].
// ---------------------------------------------------------------------------
__global__ __launch_bounds__(256) void flash_attn_f32(
    const float* __restrict__ qkv, float* __restrict__ att)
{
  const int qt = (int)gridDim.x - 1 - (int)blockIdx.x;  // big tiles first
  const int h = blockIdx.y, b = blockIdx.z;
  const int q0 = qt * 64;
  const int tid = threadIdx.x;
  const int ty = tid >> 4, tx = tid & 15;   // 16x16, 4x4 per thread

  __shared__ float Qs[64][68];   // Q transposed [d][i], pre-scaled
  __shared__ float KPs[64][68];  // K transposed [d][j], later P [j][i]
  __shared__ float Vs[64][68];   // V [j][d]

  const float scale = 0.125f;    // 1/sqrt(64)
  const int rowstride = 3 * Dd;  // 3072
  const float* base = qkv + ((size_t)b * Ss) * rowstride + h * (3 * HDd);

  // load Q tile transposed + scaled
  #pragma unroll
  for (int rep = 0; rep < 4; ++rep) {
    int i  = rep * 16 + (tid >> 4);
    int d4 = (tid & 15) * 4;
    float4 q = *(const float4*)(base + (size_t)(q0 + i) * rowstride + d4);
    Qs[d4 + 0][i] = q.x * scale; Qs[d4 + 1][i] = q.y * scale;
    Qs[d4 + 2][i] = q.z * scale; Qs[d4 + 3][i] = q.w * scale;
  }

  float m[4], l[4], o[4][4];
  #pragma unroll
  for (int r = 0; r < 4; r++) {
    m[r] = -INFINITY; l[r] = 0.f;
    #pragma unroll
    for (int c = 0; c < 4; c++) o[r][c] = 0.f;
  }

  for (int kt = 0; kt <= qt; ++kt) {
    const int k0 = kt * 64;
    // stage K (transposed) and V tiles
    #pragma unroll
    for (int rep = 0; rep < 4; ++rep) {
      int j  = rep * 16 + (tid >> 4);
      int d4 = (tid & 15) * 4;
      const float* kr = base + (size_t)(k0 + j) * rowstride + HDd + d4;
      float4 kv = *(const float4*)kr;
      KPs[d4 + 0][j] = kv.x; KPs[d4 + 1][j] = kv.y;
      KPs[d4 + 2][j] = kv.z; KPs[d4 + 3][j] = kv.w;
      *(float4*)&Vs[j][d4] =
          *(const float4*)(base + (size_t)(k0 + j) * rowstride + 2 * HDd + d4);
    }
    __syncthreads();

    // S = (Q*scale) K^T
    float s[4][4];
    #pragma unroll
    for (int r = 0; r < 4; r++)
      #pragma unroll
      for (int c = 0; c < 4; c++) s[r][c] = 0.f;
    for (int d = 0; d < 64; ++d) {
      float4 qv = *(float4*)&Qs[d][ty * 4];
      float4 kv = *(float4*)&KPs[d][tx * 4];
      float qa[4] = {qv.x, qv.y, qv.z, qv.w};
      float ka[4] = {kv.x, kv.y, kv.z, kv.w};
      #pragma unroll
      for (int r = 0; r < 4; r++)
        #pragma unroll
        for (int c = 0; c < 4; c++) s[r][c] += qa[r] * ka[c];
    }

    if (kt == qt) {  // diagonal tile: causal mask
      #pragma unroll
      for (int r = 0; r < 4; r++)
        #pragma unroll
        for (int c = 0; c < 4; c++)
          if (k0 + tx * 4 + c > q0 + ty * 4 + r) s[r][c] = -1e30f;
    }

    // online softmax (rows spread over 16 consecutive lanes)
    float p[4][4];
    #pragma unroll
    for (int r = 0; r < 4; r++) {
      float mloc = fmaxf(fmaxf(s[r][0], s[r][1]), fmaxf(s[r][2], s[r][3]));
      #pragma unroll
      for (int off = 8; off >= 1; off >>= 1)
        mloc = fmaxf(mloc, __shfl_xor(mloc, off, 16));
      float mn = fmaxf(m[r], mloc);
      float alpha = __expf(m[r] - mn);
      float rs = 0.f;
      #pragma unroll
      for (int c = 0; c < 4; c++) { p[r][c] = __expf(s[r][c] - mn); rs += p[r][c]; }
      #pragma unroll
      for (int off = 8; off >= 1; off >>= 1) rs += __shfl_xor(rs, off, 16);
      l[r] = l[r] * alpha + rs;
      m[r] = mn;
      #pragma unroll
      for (int c = 0; c < 4; c++) o[r][c] *= alpha;
    }
    __syncthreads();                 // all lanes done reading K from KPs

    // P -> LDS (transposed [j][i]) for the PV GEMM
    #pragma unroll
    for (int r = 0; r < 4; r++)
      #pragma unroll
      for (int c = 0; c < 4; c++)
        KPs[tx * 4 + c][ty * 4 + r] = p[r][c];
    __syncthreads();

    // O += P V
    for (int j = 0; j < 64; ++j) {
      float4 pv = *(float4*)&KPs[j][ty * 4];
      float4 vv = *(float4*)&Vs[j][tx * 4];
      float pa[4] = {pv.x, pv.y, pv.z, pv.w};
      float va[4] = {vv.x, vv.y, vv.z, vv.w};
      #pragma unroll
      for (int r = 0; r < 4; r++)
        #pragma unroll
        for (int c = 0; c < 4; c++) o[r][c] += pa[r] * va[c];
    }
    __syncthreads();                 // before next K/V overwrite
  }

  // normalize + write att[b*S+row][h*64 + d]
  #pragma unroll
  for (int r = 0; r < 4; r++) {
    int row = q0 + ty * 4 + r;
    float inv = 1.f / l[r];
    float4 ov = { o[r][0] * inv, o[r][1] * inv, o[r][2] * inv, o[r][3] * inv };
    *(float4*)(att + ((size_t)b * Ss + row) * Dd + h * HDd + tx * 4) = ov;
  }
}

// ---------------------------------------------------------------------------
extern "C" void kernel_launch(void* const* d_in, const int* in_sizes, int n_in,
                              void* d_out, int out_size, void* d_ws, size_t ws_size,
                              hipStream_t stream) {
  const float* x    = (const float*)d_in[0];
  // d_in[1] = mask (int32 causal tril) — causality is hardcoded in flash kernel
  const float* Wqkv = (const float*)d_in[2];
  const float* bqkv = (const float*)d_in[3];
  const float* Wout = (const float*)d_in[4];
  const float* bout = (const float*)d_in[5];
  float* out = (float*)d_out;

  float* qkv = (float*)d_ws;                          // [4096][3072]
  float* att = qkv + (size_t)4096 * 3072;             // [4096][1024]

  const int M = Bb * Ss;        // 4096
  // 1) QKV projection
  gemm_bias_f32<128, 128, 16, 8, 8>
      <<<dim3((3 * Dd) / 128, M / 128), 256, 0, stream>>>(
          x, Wqkv, bqkv, qkv, M, 3 * Dd, Dd);
  // 2) causal flash attention
  flash_attn_f32<<<dim3(Ss / 64, Hh, Bb), 256, 0, stream>>>(qkv, att);
  // 3) output projection
  gemm_bias_f32<128, 128, 16, 8, 8>
      <<<dim3(Dd / 128, M / 128), 256, 0, stream>>>(
          att, Wout, bout, out, M, Dd, Dd);
}

// Round 2
// 736.936 us; speedup vs baseline: 1.3442x; 1.3442x over previous
//
#include <hip/hip_runtime.h>
#include <math.h>

// Problem constants
constexpr int Bb = 2, Ss = 2048, Dd = 1024, Hh = 16, HDd = 64;

typedef __attribute__((ext_vector_type(8))) short bf16x8;     // 8 bf16 = 4 VGPR (MFMA A/B frag)
typedef __attribute__((ext_vector_type(4))) float f32x4;      // MFMA C/D frag
typedef __attribute__((ext_vector_type(8))) unsigned short u16x8;

// ---------------------------------------------------------------------------
// fp32 -> bf16 round-nearest-even
// ---------------------------------------------------------------------------
__device__ __forceinline__ unsigned short bf16_rn(float f) {
  unsigned int u = __float_as_uint(f);
  u += 0x7fffu + ((u >> 16) & 1u);
  return (unsigned short)(u >> 16);
}

// split fp32 array into hi/lo bf16 arrays (hi = rn(v), lo = rn(v - hi))
__global__ __launch_bounds__(256) void split_f32(
    const float* __restrict__ in, unsigned short* __restrict__ hi,
    unsigned short* __restrict__ lo, int n8) {
  int i = blockIdx.x * 256 + threadIdx.x;
  if (i >= n8) return;
  const float4* p = (const float4*)in + (size_t)i * 2;
  float4 a = p[0], b = p[1];
  float v[8] = {a.x, a.y, a.z, a.w, b.x, b.y, b.z, b.w};
  u16x8 h, l;
  #pragma unroll
  for (int j = 0; j < 8; j++) {
    unsigned short hb = bf16_rn(v[j]);
    float hf = __uint_as_float(((unsigned int)hb) << 16);
    h[j] = hb;
    l[j] = bf16_rn(v[j] - hf);
  }
  *(u16x8*)(hi + (size_t)i * 8) = h;
  *(u16x8*)(lo + (size_t)i * 8) = l;
}

// transpose W[K][N] -> Wt[N][K], split into hi/lo bf16 on the way out
__global__ __launch_bounds__(256) void transpose_split_f32(
    const float* __restrict__ W, unsigned short* __restrict__ Thi,
    unsigned short* __restrict__ Tlo, int K, int N) {
  __shared__ float tile[32][33];
  int n0 = blockIdx.x * 32, k0 = blockIdx.y * 32;
  int t = threadIdx.x;
  #pragma unroll
  for (int p = 0; p < 4; p++) {
    int idx = t + p * 256;
    int kk = idx >> 5, nn = idx & 31;
    tile[kk][nn] = W[(size_t)(k0 + kk) * N + n0 + nn];
  }
  __syncthreads();
  #pragma unroll
  for (int p = 0; p < 4; p++) {
    int idx = t + p * 256;
    int nn = idx >> 5, kk = idx & 31;
    float v = tile[kk][nn];
    unsigned short hb = bf16_rn(v);
    float hf = __uint_as_float(((unsigned int)hb) << 16);
    size_t o = (size_t)(n0 + nn) * K + k0 + kk;
    Thi[o] = hb;
    Tlo[o] = bf16_rn(v - hf);
  }
}

// ---------------------------------------------------------------------------
// Split-bf16 MFMA GEMM: C[M][N] = A[M][K] @ B[K][N] + bias, fp32-equivalent
// accuracy via acc += Ahi*Bhi + Ahi*Blo + Alo*Bhi.
// A given as row-major hi/lo bf16 [M][K]; B given TRANSPOSED hi/lo [N][K].
// 128x128 tile, 4 waves (2x2), each wave 64x64 = 4x4 frags of 16x16.
// BK=32. global_load_lds 16B staging, linear LDS; XOR granule swizzle
// (g ^= (row>>1)&3) applied to per-lane GLOBAL src addr and ds_read offsets
// -> 2-way banks (free, m136).
// ---------------------------------------------------------------------------
typedef __attribute__((address_space(3))) unsigned int lds_u32;
typedef const __attribute__((address_space(1))) unsigned int glb_u32;
__device__ __forceinline__ void gload16(const void* g, void* l) {
  __builtin_amdgcn_global_load_lds((glb_u32*)g, (lds_u32*)l, 16, 0, 0);
}

template<int KD>
__global__ __launch_bounds__(256) void gemm_split_bf16(
    const unsigned short* __restrict__ Ahi, const unsigned short* __restrict__ Alo,
    const unsigned short* __restrict__ Bhi, const unsigned short* __restrict__ Blo,
    const float* __restrict__ bias, float* __restrict__ C, int N)
{
  __shared__ unsigned short lds[4 * 4096];  // Ahi|Alo|Bhi|Blo tiles, 128x32 each
  const int tid = threadIdx.x;
  const int lane = tid & 63, wid = tid >> 6;
  const int m0 = blockIdx.y * 128, n0 = blockIdx.x * 128;
  const int wrow = wid >> 1, wcol = wid & 1;
  const int lrow = lane & 15, g = lane >> 4;

  // ---- staging geometry: 512 granules (16B) per tile; this thread covers
  // granule o0 (issue 0) and o1 (issue 1) of every tile.
  const int o0 = wid * 128 + lane, o1 = o0 + 64;
  const int r0 = o0 >> 2, G0 = (o0 & 3) ^ ((r0 >> 1) & 3);
  const int r1 = o1 >> 2, G1 = (o1 & 3) ^ ((r1 >> 1) & 3);
  const unsigned short* sA0h = Ahi + (size_t)(m0 + r0) * KD + G0 * 8;
  const unsigned short* sA1h = Ahi + (size_t)(m0 + r1) * KD + G1 * 8;
  const unsigned short* sA0l = Alo + (size_t)(m0 + r0) * KD + G0 * 8;
  const unsigned short* sA1l = Alo + (size_t)(m0 + r1) * KD + G1 * 8;
  const unsigned short* sB0h = Bhi + (size_t)(n0 + r0) * KD + G0 * 8;
  const unsigned short* sB1h = Bhi + (size_t)(n0 + r1) * KD + G1 * 8;
  const unsigned short* sB0l = Blo + (size_t)(n0 + r0) * KD + G0 * 8;
  const unsigned short* sB1l = Blo + (size_t)(n0 + r1) * KD + G1 * 8;
  // wave-uniform LDS dests (HW adds lane*16B)
  unsigned short* dA0h = lds +     0 + wid * 1024;
  unsigned short* dA1h = dA0h + 512;
  unsigned short* dA0l = lds +  4096 + wid * 1024;
  unsigned short* dA1l = dA0l + 512;
  unsigned short* dB0h = lds +  8192 + wid * 1024;
  unsigned short* dB1h = dB0h + 512;
  unsigned short* dB0l = lds + 12288 + wid * 1024;
  unsigned short* dB1l = dB0l + 512;

  // ---- fragment ds_read offsets (constant across K-steps)
  int offA[4], offB[4];
  #pragma unroll
  for (int m = 0; m < 4; m++) {
    int row = wrow * 64 + m * 16 + lrow;
    offA[m] = row * 32 + ((g ^ ((row >> 1) & 3)) * 8);
  }
  #pragma unroll
  for (int n = 0; n < 4; n++) {
    int row = wcol * 64 + n * 16 + lrow;
    offB[n] = row * 32 + ((g ^ ((row >> 1) & 3)) * 8);
  }

  f32x4 acc[4][4];
  #pragma unroll
  for (int m = 0; m < 4; m++)
    #pragma unroll
    for (int n = 0; n < 4; n++) acc[m][n] = (f32x4){0.f, 0.f, 0.f, 0.f};

  for (int k0 = 0; k0 < KD; k0 += 32) {
    gload16(sA0h + k0, dA0h); gload16(sA1h + k0, dA1h);
    gload16(sA0l + k0, dA0l); gload16(sA1l + k0, dA1l);
    gload16(sB0h + k0, dB0h); gload16(sB1h + k0, dB1h);
    gload16(sB0l + k0, dB0l); gload16(sB1l + k0, dB1l);
    __syncthreads();  // compiler drains vmcnt here

    bf16x8 ah[4], al[4], bh[4], bl[4];
    #pragma unroll
    for (int m = 0; m < 4; m++) {
      ah[m] = *(const bf16x8*)(lds +     0 + offA[m]);
      al[m] = *(const bf16x8*)(lds +  4096 + offA[m]);
    }
    #pragma unroll
    for (int n = 0; n < 4; n++) {
      bh[n] = *(const bf16x8*)(lds +  8192 + offB[n]);
      bl[n] = *(const bf16x8*)(lds + 12288 + offB[n]);
    }
    #pragma unroll
    for (int m = 0; m < 4; m++)
      #pragma unroll
      for (int n = 0; n < 4; n++) {
        acc[m][n] = __builtin_amdgcn_mfma_f32_16x16x32_bf16(ah[m], bh[n], acc[m][n], 0, 0, 0);
        acc[m][n] = __builtin_amdgcn_mfma_f32_16x16x32_bf16(ah[m], bl[n], acc[m][n], 0, 0, 0);
        acc[m][n] = __builtin_amdgcn_mfma_f32_16x16x32_bf16(al[m], bh[n], acc[m][n], 0, 0, 0);
      }
    __syncthreads();
  }

  // ---- epilogue: C/D layout col = lane&15, row = (lane>>4)*4 + reg (m89-verified)
  #pragma unroll
  for (int n = 0; n < 4; n++) {
    int gcol = n0 + wcol * 64 + n * 16 + lrow;
    float bv = bias[gcol];
    #pragma unroll
    for (int m = 0; m < 4; m++) {
      f32x4 a = acc[m][n];
      #pragma unroll
      for (int r = 0; r < 4; r++) {
        int grow = m0 + wrow * 64 + m * 16 + g * 4 + r;
        C[(size_t)grow * N + gcol] = a[r] + bv;
      }
    }
  }
}

// ---------------------------------------------------------------------------
// Flash attention fp32 (unchanged from round 1 — next round's target).
// ---------------------------------------------------------------------------
__global__ __launch_bounds__(256) void flash_attn_f32(
    const float* __restrict__ qkv, float* __restrict__ att)
{
  const int qt = (int)gridDim.x - 1 - (int)blockIdx.x;
  const int h = blockIdx.y, b = blockIdx.z;
  const int q0 = qt * 64;
  const int tid = threadIdx.x;
  const int ty = tid >> 4, tx = tid & 15;

  __shared__ float Qs[64][68];
  __shared__ float KPs[64][68];
  __shared__ float Vs[64][68];

  const float scale = 0.125f;
  const int rowstride = 3 * Dd;
  const float* base = qkv + ((size_t)b * Ss) * rowstride + h * (3 * HDd);

  #pragma unroll
  for (int rep = 0; rep < 4; ++rep) {
    int i  = rep * 16 + (tid >> 4);
    int d4 = (tid & 15) * 4;
    float4 q = *(const float4*)(base + (size_t)(q0 + i) * rowstride + d4);
    Qs[d4 + 0][i] = q.x * scale; Qs[d4 + 1][i] = q.y * scale;
    Qs[d4 + 2][i] = q.z * scale; Qs[d4 + 3][i] = q.w * scale;
  }

  float m[4], l[4], o[4][4];
  #pragma unroll
  for (int r = 0; r < 4; r++) {
    m[r] = -INFINITY; l[r] = 0.f;
    #pragma unroll
    for (int c = 0; c < 4; c++) o[r][c] = 0.f;
  }

  for (int kt = 0; kt <= qt; ++kt) {
    const int k0 = kt * 64;
    #pragma unroll
    for (int rep = 0; rep < 4; ++rep) {
      int j  = rep * 16 + (tid >> 4);
      int d4 = (tid & 15) * 4;
      const float* kr = base + (size_t)(k0 + j) * rowstride + HDd + d4;
      float4 kv = *(const float4*)kr;
      KPs[d4 + 0][j] = kv.x; KPs[d4 + 1][j] = kv.y;
      KPs[d4 + 2][j] = kv.z; KPs[d4 + 3][j] = kv.w;
      *(float4*)&Vs[j][d4] =
          *(const float4*)(base + (size_t)(k0 + j) * rowstride + 2 * HDd + d4);
    }
    __syncthreads();

    float s[4][4];
    #pragma unroll
    for (int r = 0; r < 4; r++)
      #pragma unroll
      for (int c = 0; c < 4; c++) s[r][c] = 0.f;
    for (int d = 0; d < 64; ++d) {
      float4 qv = *(float4*)&Qs[d][ty * 4];
      float4 kv = *(float4*)&KPs[d][tx * 4];
      float qa[4] = {qv.x, qv.y, qv.z, qv.w};
      float ka[4] = {kv.x, kv.y, kv.z, kv.w};
      #pragma unroll
      for (int r = 0; r < 4; r++)
        #pragma unroll
        for (int c = 0; c < 4; c++) s[r][c] += qa[r] * ka[c];
    }

    if (kt == qt) {
      #pragma unroll
      for (int r = 0; r < 4; r++)
        #pragma unroll
        for (int c = 0; c < 4; c++)
          if (k0 + tx * 4 + c > q0 + ty * 4 + r) s[r][c] = -1e30f;
    }

    float p[4][4];
    #pragma unroll
    for (int r = 0; r < 4; r++) {
      float mloc = fmaxf(fmaxf(s[r][0], s[r][1]), fmaxf(s[r][2], s[r][3]));
      #pragma unroll
      for (int off = 8; off >= 1; off >>= 1)
        mloc = fmaxf(mloc, __shfl_xor(mloc, off, 16));
      float mn = fmaxf(m[r], mloc);
      float alpha = __expf(m[r] - mn);
      float rs = 0.f;
      #pragma unroll
      for (int c = 0; c < 4; c++) { p[r][c] = __expf(s[r][c] - mn); rs += p[r][c]; }
      #pragma unroll
      for (int off = 8; off >= 1; off >>= 1) rs += __shfl_xor(rs, off, 16);
      l[r] = l[r] * alpha + rs;
      m[r] = mn;
      #pragma unroll
      for (int c = 0; c < 4; c++) o[r][c] *= alpha;
    }
    __syncthreads();

    #pragma unroll
    for (int r = 0; r < 4; r++)
      #pragma unroll
      for (int c = 0; c < 4; c++)
        KPs[tx * 4 + c][ty * 4 + r] = p[r][c];
    __syncthreads();

    for (int j = 0; j < 64; ++j) {
      float4 pv = *(float4*)&KPs[j][ty * 4];
      float4 vv = *(float4*)&Vs[j][tx * 4];
      float pa[4] = {pv.x, pv.y, pv.z, pv.w};
      float va[4] = {vv.x, vv.y, vv.z, vv.w};
      #pragma unroll
      for (int r = 0; r < 4; r++)
        #pragma unroll
        for (int c = 0; c < 4; c++) o[r][c] += pa[r] * va[c];
    }
    __syncthreads();
  }

  #pragma unroll
  for (int r = 0; r < 4; r++) {
    int row = q0 + ty * 4 + r;
    float inv = 1.f / l[r];
    float4 ov = { o[r][0] * inv, o[r][1] * inv, o[r][2] * inv, o[r][3] * inv };
    *(float4*)(att + ((size_t)b * Ss + row) * Dd + h * HDd + tx * 4) = ov;
  }
}

// ---------------------------------------------------------------------------
extern "C" void kernel_launch(void* const* d_in, const int* in_sizes, int n_in,
                              void* d_out, int out_size, void* d_ws, size_t ws_size,
                              hipStream_t stream) {
  const float* x    = (const float*)d_in[0];
  // d_in[1] = causal mask (hardcoded in flash kernel)
  const float* Wqkv = (const float*)d_in[2];
  const float* bqkv = (const float*)d_in[3];
  const float* Wout = (const float*)d_in[4];
  const float* bout = (const float*)d_in[5];
  float* out = (float*)d_out;

  char* ws = (char*)d_ws;
  // workspace layout (100.66 MB total)
  float* qkv = (float*)(ws);                                  // 4096x3072 f32
  float* att = (float*)(ws + 50331648);                       // 4096x1024 f32
  unsigned short* xhi = (unsigned short*)(ws + 67108864);     // 4096x1024 bf16 (reused for att)
  unsigned short* xlo = (unsigned short*)(ws + 75497472);
  unsigned short* wqh = (unsigned short*)(ws + 83886080);     // 3072x1024 bf16 (Wqkv^T)
  unsigned short* wql = (unsigned short*)(ws + 90177536);
  unsigned short* woh = (unsigned short*)(ws + 96468992);     // 1024x1024 bf16 (Wout^T)
  unsigned short* wol = (unsigned short*)(ws + 98566144);

  const int M = Bb * Ss;  // 4096

  // prep: split x, transpose+split weights
  split_f32<<<(M * Dd / 8) / 256, 256, 0, stream>>>(x, xhi, xlo, M * Dd / 8);
  transpose_split_f32<<<dim3(3 * Dd / 32, Dd / 32), 256, 0, stream>>>(Wqkv, wqh, wql, Dd, 3 * Dd);
  transpose_split_f32<<<dim3(Dd / 32, Dd / 32), 256, 0, stream>>>(Wout, woh, wol, Dd, Dd);

  // 1) QKV projection (M=4096, N=3072, K=1024)
  gemm_split_bf16<1024><<<dim3(3 * Dd / 128, M / 128), 256, 0, stream>>>(
      xhi, xlo, wqh, wql, bqkv, qkv, 3 * Dd);

  // 2) causal flash attention (fp32, unchanged)
  flash_attn_f32<<<dim3(Ss / 64, Hh, Bb), 256, 0, stream>>>(qkv, att);

  // 3) split att, then output projection (M=4096, N=1024, K=1024)
  split_f32<<<(M * Dd / 8) / 256, 256, 0, stream>>>(att, xhi, xlo, M * Dd / 8);
  gemm_split_bf16<1024><<<dim3(Dd / 128, M / 128), 256, 0, stream>>>(
      xhi, xlo, woh, wol, bout, out, Dd);
}

// Round 3
// 407.608 us; speedup vs baseline: 2.4303x; 1.8080x over previous
//
#include <hip/hip_runtime.h>
#include <math.h>

// Problem constants
constexpr int Bb = 2, Ss = 2048, Dd = 1024, Hh = 16, HDd = 64;

typedef __attribute__((ext_vector_type(8))) short bf16x8;     // MFMA A/B frag
typedef __attribute__((ext_vector_type(4))) float f32x4;      // MFMA C/D frag
typedef __attribute__((ext_vector_type(8))) unsigned short u16x8;
typedef __attribute__((ext_vector_type(4))) unsigned short u16x4;

__device__ __forceinline__ unsigned short bf16_rn(float f) {
  unsigned int u = __float_as_uint(f);
  u += 0x7fffu + ((u >> 16) & 1u);
  return (unsigned short)(u >> 16);
}
__device__ __forceinline__ float bf16_f(unsigned short h) {
  return __uint_as_float(((unsigned int)h) << 16);
}

// ---------------------------------------------------------------------------
// split fp32 array into hi/lo bf16 arrays
// ---------------------------------------------------------------------------
__global__ __launch_bounds__(256) void split_f32(
    const float* __restrict__ in, unsigned short* __restrict__ hi,
    unsigned short* __restrict__ lo, int n8) {
  int i = blockIdx.x * 256 + threadIdx.x;
  if (i >= n8) return;
  const float4* p = (const float4*)in + (size_t)i * 2;
  float4 a = p[0], b = p[1];
  float v[8] = {a.x, a.y, a.z, a.w, b.x, b.y, b.z, b.w};
  u16x8 h, l;
  #pragma unroll
  for (int j = 0; j < 8; j++) {
    unsigned short hb = bf16_rn(v[j]);
    h[j] = hb;
    l[j] = bf16_rn(v[j] - bf16_f(hb));
  }
  *(u16x8*)(hi + (size_t)i * 8) = h;
  *(u16x8*)(lo + (size_t)i * 8) = l;
}

// transpose W[K][N] -> Wt[N][K], split into hi/lo bf16
__global__ __launch_bounds__(256) void transpose_split_f32(
    const float* __restrict__ W, unsigned short* __restrict__ Thi,
    unsigned short* __restrict__ Tlo, int K, int N) {
  __shared__ float tile[32][33];
  int n0 = blockIdx.x * 32, k0 = blockIdx.y * 32;
  int t = threadIdx.x;
  #pragma unroll
  for (int p = 0; p < 4; p++) {
    int idx = t + p * 256;
    int kk = idx >> 5, nn = idx & 31;
    tile[kk][nn] = W[(size_t)(k0 + kk) * N + n0 + nn];
  }
  __syncthreads();
  #pragma unroll
  for (int p = 0; p < 4; p++) {
    int idx = t + p * 256;
    int nn = idx >> 5, kk = idx & 31;
    float v = tile[kk][nn];
    unsigned short hb = bf16_rn(v);
    size_t o = (size_t)(n0 + nn) * K + k0 + kk;
    Thi[o] = hb;
    Tlo[o] = bf16_rn(v - bf16_f(hb));
  }
}

// ---------------------------------------------------------------------------
typedef __attribute__((address_space(3))) unsigned int lds_u32;
typedef const __attribute__((address_space(1))) unsigned int glb_u32;
__device__ __forceinline__ void gload16(const void* g, void* l) {
  __builtin_amdgcn_global_load_lds((glb_u32*)g, (lds_u32*)l, 16, 0, 0);
}

// ---------------------------------------------------------------------------
// Split-bf16 MFMA GEMM core (m97 structure). Shared by both GEMMs; epilogues
// differ. A row-major hi/lo [M][K]; B transposed hi/lo [N][K].
// ---------------------------------------------------------------------------
#define GEMM_CORE(KD)                                                          \
  __shared__ unsigned short lds[4 * 4096];                                     \
  const int tid = threadIdx.x;                                                 \
  const int lane = tid & 63, wid = tid >> 6;                                   \
  const int m0 = blockIdx.y * 128, n0 = blockIdx.x * 128;                      \
  const int wrow = wid >> 1, wcol = wid & 1;                                   \
  const int lrow = lane & 15, g = lane >> 4;                                   \
  const int o0 = wid * 128 + lane, o1 = o0 + 64;                               \
  const int r0 = o0 >> 2, G0 = (o0 & 3) ^ ((r0 >> 1) & 3);                     \
  const int r1 = o1 >> 2, G1 = (o1 & 3) ^ ((r1 >> 1) & 3);                     \
  const unsigned short* sA0h = Ahi + (size_t)(m0 + r0) * KD + G0 * 8;          \
  const unsigned short* sA1h = Ahi + (size_t)(m0 + r1) * KD + G1 * 8;          \
  const unsigned short* sA0l = Alo + (size_t)(m0 + r0) * KD + G0 * 8;          \
  const unsigned short* sA1l = Alo + (size_t)(m0 + r1) * KD + G1 * 8;          \
  const unsigned short* sB0h = Bhi + (size_t)(n0 + r0) * KD + G0 * 8;          \
  const unsigned short* sB1h = Bhi + (size_t)(n0 + r1) * KD + G1 * 8;          \
  const unsigned short* sB0l = Blo + (size_t)(n0 + r0) * KD + G0 * 8;          \
  const unsigned short* sB1l = Blo + (size_t)(n0 + r1) * KD + G1 * 8;          \
  unsigned short* dA0h = lds + 0 + wid * 1024;                                 \
  unsigned short* dA1h = dA0h + 512;                                           \
  unsigned short* dA0l = lds + 4096 + wid * 1024;                              \
  unsigned short* dA1l = dA0l + 512;                                           \
  unsigned short* dB0h = lds + 8192 + wid * 1024;                              \
  unsigned short* dB1h = dB0h + 512;                                           \
  unsigned short* dB0l = lds + 12288 + wid * 1024;                             \
  unsigned short* dB1l = dB0l + 512;                                           \
  int offA[4], offB[4];                                                        \
  _Pragma("unroll")                                                            \
  for (int m = 0; m < 4; m++) {                                                \
    int row = wrow * 64 + m * 16 + lrow;                                       \
    offA[m] = row * 32 + ((g ^ ((row >> 1) & 3)) * 8);                         \
  }                                                                            \
  _Pragma("unroll")                                                            \
  for (int n = 0; n < 4; n++) {                                                \
    int row = wcol * 64 + n * 16 + lrow;                                       \
    offB[n] = row * 32 + ((g ^ ((row >> 1) & 3)) * 8);                         \
  }                                                                            \
  f32x4 acc[4][4];                                                             \
  _Pragma("unroll")                                                            \
  for (int m = 0; m < 4; m++)                                                  \
    _Pragma("unroll")                                                          \
    for (int n = 0; n < 4; n++) acc[m][n] = (f32x4){0.f, 0.f, 0.f, 0.f};       \
  for (int k0 = 0; k0 < KD; k0 += 32) {                                        \
    gload16(sA0h + k0, dA0h); gload16(sA1h + k0, dA1h);                        \
    gload16(sA0l + k0, dA0l); gload16(sA1l + k0, dA1l);                        \
    gload16(sB0h + k0, dB0h); gload16(sB1h + k0, dB1h);                        \
    gload16(sB0l + k0, dB0l); gload16(sB1l + k0, dB1l);                        \
    __syncthreads();                                                           \
    bf16x8 ah[4], al[4], bh[4], bl[4];                                         \
    _Pragma("unroll")                                                          \
    for (int m = 0; m < 4; m++) {                                              \
      ah[m] = *(const bf16x8*)(lds + 0 + offA[m]);                             \
      al[m] = *(const bf16x8*)(lds + 4096 + offA[m]);                          \
    }                                                                          \
    _Pragma("unroll")                                                          \
    for (int n = 0; n < 4; n++) {                                              \
      bh[n] = *(const bf16x8*)(lds + 8192 + offB[n]);                          \
      bl[n] = *(const bf16x8*)(lds + 12288 + offB[n]);                         \
    }                                                                          \
    _Pragma("unroll")                                                          \
    for (int m = 0; m < 4; m++)                                                \
      _Pragma("unroll")                                                        \
      for (int n = 0; n < 4; n++) {                                            \
        acc[m][n] = __builtin_amdgcn_mfma_f32_16x16x32_bf16(ah[m], bh[n], acc[m][n], 0, 0, 0); \
        acc[m][n] = __builtin_amdgcn_mfma_f32_16x16x32_bf16(ah[m], bl[n], acc[m][n], 0, 0, 0); \
        acc[m][n] = __builtin_amdgcn_mfma_f32_16x16x32_bf16(al[m], bh[n], acc[m][n], 0, 0, 0); \
      }                                                                        \
    __syncthreads();                                                           \
  }

// GEMM with plain f32 output (used for out-projection)
template<int KD>
__global__ __launch_bounds__(256) void gemm_split_bf16(
    const unsigned short* __restrict__ Ahi, const unsigned short* __restrict__ Alo,
    const unsigned short* __restrict__ Bhi, const unsigned short* __restrict__ Blo,
    const float* __restrict__ bias, float* __restrict__ C, int N)
{
  GEMM_CORE(KD)
  #pragma unroll
  for (int n = 0; n < 4; n++) {
    int gcol = n0 + wcol * 64 + n * 16 + lrow;
    float bv = bias[gcol];
    #pragma unroll
    for (int m = 0; m < 4; m++) {
      f32x4 a = acc[m][n];
      #pragma unroll
      for (int r = 0; r < 4; r++) {
        int grow = m0 + wrow * 64 + m * 16 + g * 4 + r;
        C[(size_t)grow * N + gcol] = a[r] + bv;
      }
    }
  }
}

// QKV GEMM: epilogue scatters into per-head split-bf16 Q/K/Vt arrays.
// col c in [0,3072): h=c/192, inner=c%192, part=inner/64, d=inner%64.
// Q pre-scaled by 1/sqrt(HD)=0.125. Vt stored transposed [BH][64][S].
template<int KD>
__global__ __launch_bounds__(256) void gemm_qkv(
    const unsigned short* __restrict__ Ahi, const unsigned short* __restrict__ Alo,
    const unsigned short* __restrict__ Bhi, const unsigned short* __restrict__ Blo,
    const float* __restrict__ bias,
    unsigned short* __restrict__ Qh, unsigned short* __restrict__ Ql,
    unsigned short* __restrict__ Kh, unsigned short* __restrict__ Kl,
    unsigned short* __restrict__ Vth, unsigned short* __restrict__ Vtl)
{
  GEMM_CORE(KD)
  const int bidx = m0 >> 11;
  const int sbase = (m0 & 2047) + wrow * 64 + g * 4;   // + m*16 + r
  #pragma unroll
  for (int n = 0; n < 4; n++) {
    int gcol = n0 + wcol * 64 + n * 16 + lrow;
    unsigned hh = (unsigned)gcol / 192u;               // head (wave-uniform per n)
    int inner = gcol - (int)hh * 192;
    int part = inner >> 6;                             // 0=q 1=k 2=v (wave-uniform)
    int d = inner & 63;
    float bv = bias[gcol];
    size_t base = (size_t)(bidx * 16 + (int)hh) * 131072;
    #pragma unroll
    for (int m = 0; m < 4; m++) {
      f32x4 a = acc[m][n];
      int s0 = sbase + m * 16;
      if (part == 0) {
        #pragma unroll
        for (int r = 0; r < 4; r++) {
          float v = (a[r] + bv) * 0.125f;
          unsigned short hi = bf16_rn(v);
          size_t ix = base + (size_t)(s0 + r) * 64 + d;
          Qh[ix] = hi; Ql[ix] = bf16_rn(v - bf16_f(hi));
        }
      } else if (part == 1) {
        #pragma unroll
        for (int r = 0; r < 4; r++) {
          float v = a[r] + bv;
          unsigned short hi = bf16_rn(v);
          size_t ix = base + (size_t)(s0 + r) * 64 + d;
          Kh[ix] = hi; Kl[ix] = bf16_rn(v - bf16_f(hi));
        }
      } else {
        u16x4 hv, lv;
        #pragma unroll
        for (int r = 0; r < 4; r++) {
          float v = a[r] + bv;
          hv[r] = bf16_rn(v);
          lv[r] = bf16_rn(v - bf16_f(hv[r]));
        }
        size_t ix = base + (size_t)d * 2048 + s0;
        *(u16x4*)(Vth + ix) = hv;
        *(u16x4*)(Vtl + ix) = lv;
      }
    }
  }
}

// ---------------------------------------------------------------------------
// MFMA flash attention. Block = (qtile of 128 rows, h, b); 4 waves x 32 rows.
// KV tiles 64x64 hi/lo staged via global_load_lds with granule-XOR swizzle
// g^(row&7) (8 granules/row; kills the 128B-stride 32-way conflict).
// QK^T: 3-term split (QhKh+QhKl+QlKh). Softmax fp32 online (16-lane shfl).
// P bf16 -> wave-private LDS (same swizzle). PV: P*(Vh+Vl).
// Output: split-bf16 att rows [B*S][1024].
// ---------------------------------------------------------------------------
__global__ __launch_bounds__(256) void flash_attn_mfma(
    const unsigned short* __restrict__ Qh, const unsigned short* __restrict__ Ql,
    const unsigned short* __restrict__ Kh, const unsigned short* __restrict__ Kl,
    const unsigned short* __restrict__ Vth, const unsigned short* __restrict__ Vtl,
    unsigned short* __restrict__ atthi, unsigned short* __restrict__ attlo)
{
  const int qt = (int)gridDim.x - 1 - (int)blockIdx.x;   // big tiles first
  const int h = blockIdx.y, b = blockIdx.z;
  const int bh = b * Hh + h;
  const int q0 = qt * 128;
  const int tid = threadIdx.x, lane = tid & 63, wid = tid >> 6;
  const int q0w = q0 + wid * 32;
  const int lrow = lane & 15, lg = lane >> 4;

  __shared__ unsigned short KH[4096], KL[4096], VH[4096], VL[4096];
  __shared__ unsigned short Pbuf[4][2048];

  const size_t hb = (size_t)bh * 131072;
  const unsigned short* qhb = Qh + hb;
  const unsigned short* qlb = Ql + hb;
  const unsigned short* khb = Kh + hb;
  const unsigned short* klb = Kl + hb;
  const unsigned short* vhb = Vth + hb;
  const unsigned short* vlb = Vtl + hb;

  // Q fragments hoisted to registers (pre-scaled by 0.125 in GEMM epilogue)
  bf16x8 qfh[2][2], qfl[2][2];
  #pragma unroll
  for (int mi = 0; mi < 2; mi++)
    #pragma unroll
    for (int ks = 0; ks < 2; ks++) {
      int off = (q0w + mi * 16 + lrow) * 64 + ks * 32 + lg * 8;
      qfh[mi][ks] = *(const bf16x8*)(qhb + off);
      qfl[mi][ks] = *(const bf16x8*)(qlb + off);
    }

  // LDS fragment offsets (elements), swizzle g^(row&7)
  int offK[4][2], offV[4][2], offP[2][2];
  #pragma unroll
  for (int ci = 0; ci < 4; ci++)
    #pragma unroll
    for (int ks = 0; ks < 2; ks++) {
      int row = ci * 16 + lrow;
      int sw = ((ks * 4 + lg) ^ (row & 7)) * 8;
      offK[ci][ks] = row * 64 + sw;
      offV[ci][ks] = row * 64 + sw;
    }
  #pragma unroll
  for (int mi = 0; mi < 2; mi++)
    #pragma unroll
    for (int ks = 0; ks < 2; ks++) {
      int row = mi * 16 + lrow;
      offP[mi][ks] = row * 64 + (((ks * 4 + lg) ^ (row & 7)) * 8);
    }

  // staging: thread covers granules o=tid and o=tid+256 of each [64][64] tile
  const int o0 = tid, o1 = tid + 256;
  const int sr0 = o0 >> 3, sg0 = ((o0 & 7) ^ (sr0 & 7)) * 8;
  const int sr1 = o1 >> 3, sg1 = ((o1 & 7) ^ (sr1 & 7)) * 8;

  float m_[2][4], l_[2][4];
  f32x4 oacc[2][4];
  #pragma unroll
  for (int mi = 0; mi < 2; mi++)
    #pragma unroll
    for (int r = 0; r < 4; r++) {
      m_[mi][r] = -INFINITY; l_[mi][r] = 0.f;
    }
  #pragma unroll
  for (int mi = 0; mi < 2; mi++)
    #pragma unroll
    for (int di = 0; di < 4; di++) oacc[mi][di] = (f32x4){0.f, 0.f, 0.f, 0.f};

  unsigned short* Pw = Pbuf[wid];
  const int kvend = q0 + 128;

  for (int kv0 = 0; kv0 < kvend; kv0 += 64) {
    // stage K,V hi/lo (all threads; linear LDS dest, pre-swizzled global src)
    gload16(khb + (size_t)(kv0 + sr0) * 64 + sg0, KH + wid * 512);
    gload16(khb + (size_t)(kv0 + sr1) * 64 + sg1, KH + 2048 + wid * 512);
    gload16(klb + (size_t)(kv0 + sr0) * 64 + sg0, KL + wid * 512);
    gload16(klb + (size_t)(kv0 + sr1) * 64 + sg1, KL + 2048 + wid * 512);
    gload16(vhb + (size_t)sr0 * 2048 + kv0 + sg0, VH + wid * 512);
    gload16(vhb + (size_t)sr1 * 2048 + kv0 + sg1, VH + 2048 + wid * 512);
    gload16(vlb + (size_t)sr0 * 2048 + kv0 + sg0, VL + wid * 512);
    gload16(vlb + (size_t)sr1 * 2048 + kv0 + sg1, VL + 2048 + wid * 512);
    __syncthreads();

    if (kv0 <= q0w + 31) {            // wave-uniform: skip fully-masked tiles
      // S = Q K^T (3-term split)
      f32x4 sf[2][4];
      #pragma unroll
      for (int mi = 0; mi < 2; mi++)
        #pragma unroll
        for (int ci = 0; ci < 4; ci++) sf[mi][ci] = (f32x4){0.f, 0.f, 0.f, 0.f};
      #pragma unroll
      for (int ci = 0; ci < 4; ci++) {
        bf16x8 kh0 = *(const bf16x8*)(KH + offK[ci][0]);
        bf16x8 kh1 = *(const bf16x8*)(KH + offK[ci][1]);
        bf16x8 kl0 = *(const bf16x8*)(KL + offK[ci][0]);
        bf16x8 kl1 = *(const bf16x8*)(KL + offK[ci][1]);
        #pragma unroll
        for (int mi = 0; mi < 2; mi++) {
          f32x4 s = sf[mi][ci];
          s = __builtin_amdgcn_mfma_f32_16x16x32_bf16(qfh[mi][0], kh0, s, 0, 0, 0);
          s = __builtin_amdgcn_mfma_f32_16x16x32_bf16(qfh[mi][1], kh1, s, 0, 0, 0);
          s = __builtin_amdgcn_mfma_f32_16x16x32_bf16(qfh[mi][0], kl0, s, 0, 0, 0);
          s = __builtin_amdgcn_mfma_f32_16x16x32_bf16(qfh[mi][1], kl1, s, 0, 0, 0);
          s = __builtin_amdgcn_mfma_f32_16x16x32_bf16(qfl[mi][0], kh0, s, 0, 0, 0);
          s = __builtin_amdgcn_mfma_f32_16x16x32_bf16(qfl[mi][1], kh1, s, 0, 0, 0);
          sf[mi][ci] = s;
        }
      }

      // causal mask on straddling tiles
      if (kv0 + 63 > q0w) {
        #pragma unroll
        for (int mi = 0; mi < 2; mi++)
          #pragma unroll
          for (int ci = 0; ci < 4; ci++)
            #pragma unroll
            for (int r = 0; r < 4; r++) {
              int q = q0w + mi * 16 + lg * 4 + r;
              int kv = kv0 + ci * 16 + lrow;
              if (kv > q) sf[mi][ci][r] = -1e30f;
            }
      }

      // online softmax (fp32); p values overwrite sf
      #pragma unroll
      for (int mi = 0; mi < 2; mi++)
        #pragma unroll
        for (int r = 0; r < 4; r++) {
          float mx = fmaxf(fmaxf(sf[mi][0][r], sf[mi][1][r]),
                           fmaxf(sf[mi][2][r], sf[mi][3][r]));
          mx = fmaxf(mx, __shfl_xor(mx, 1));
          mx = fmaxf(mx, __shfl_xor(mx, 2));
          mx = fmaxf(mx, __shfl_xor(mx, 4));
          mx = fmaxf(mx, __shfl_xor(mx, 8));
          float mn = fmaxf(m_[mi][r], mx);
          float alpha = __expf(m_[mi][r] - mn);
          m_[mi][r] = mn;
          float rs = 0.f;
          #pragma unroll
          for (int ci = 0; ci < 4; ci++) {
            float p = __expf(sf[mi][ci][r] - mn);
            sf[mi][ci][r] = p;
            rs += p;
          }
          rs += __shfl_xor(rs, 1);
          rs += __shfl_xor(rs, 2);
          rs += __shfl_xor(rs, 4);
          rs += __shfl_xor(rs, 8);
          l_[mi][r] = l_[mi][r] * alpha + rs;
          #pragma unroll
          for (int di = 0; di < 4; di++) oacc[mi][di][r] *= alpha;
        }

      // P -> wave-private LDS as bf16 (swizzled); no barrier needed
      #pragma unroll
      for (int mi = 0; mi < 2; mi++)
        #pragma unroll
        for (int ci = 0; ci < 4; ci++) {
          int colb = ci * 16 + lrow;
          int gcol = colb >> 3, crem = colb & 7;
          #pragma unroll
          for (int r = 0; r < 4; r++) {
            int rr = mi * 16 + lg * 4 + r;
            Pw[rr * 64 + ((gcol ^ (rr & 7)) * 8) + crem] = bf16_rn(sf[mi][ci][r]);
          }
        }

      // O += P (Vh + Vl)
      bf16x8 pa[2][2];
      #pragma unroll
      for (int mi = 0; mi < 2; mi++)
        #pragma unroll
        for (int ks = 0; ks < 2; ks++)
          pa[mi][ks] = *(const bf16x8*)(Pw + offP[mi][ks]);
      #pragma unroll
      for (int di = 0; di < 4; di++) {
        bf16x8 vh0 = *(const bf16x8*)(VH + offV[di][0]);
        bf16x8 vh1 = *(const bf16x8*)(VH + offV[di][1]);
        bf16x8 vl0 = *(const bf16x8*)(VL + offV[di][0]);
        bf16x8 vl1 = *(const bf16x8*)(VL + offV[di][1]);
        #pragma unroll
        for (int mi = 0; mi < 2; mi++) {
          f32x4 o = oacc[mi][di];
          o = __builtin_amdgcn_mfma_f32_16x16x32_bf16(pa[mi][0], vh0, o, 0, 0, 0);
          o = __builtin_amdgcn_mfma_f32_16x16x32_bf16(pa[mi][1], vh1, o, 0, 0, 0);
          o = __builtin_amdgcn_mfma_f32_16x16x32_bf16(pa[mi][0], vl0, o, 0, 0, 0);
          o = __builtin_amdgcn_mfma_f32_16x16x32_bf16(pa[mi][1], vl1, o, 0, 0, 0);
          oacc[mi][di] = o;
        }
      }
    }
    __syncthreads();
  }

  // epilogue: normalize, write split-bf16 att [B*S][1024]
  #pragma unroll
  for (int mi = 0; mi < 2; mi++) {
    float inv[4];
    #pragma unroll
    for (int r = 0; r < 4; r++) inv[r] = 1.f / l_[mi][r];
    #pragma unroll
    for (int di = 0; di < 4; di++) {
      f32x4 o = oacc[mi][di];
      #pragma unroll
      for (int r = 0; r < 4; r++) {
        float v = o[r] * inv[r];
        int srow = q0w + mi * 16 + lg * 4 + r;
        size_t idx = ((size_t)b * Ss + srow) * 1024 + h * 64 + di * 16 + lrow;
        unsigned short hi = bf16_rn(v);
        atthi[idx] = hi;
        attlo[idx] = bf16_rn(v - bf16_f(hi));
      }
    }
  }
}

// ---------------------------------------------------------------------------
extern "C" void kernel_launch(void* const* d_in, const int* in_sizes, int n_in,
                              void* d_out, int out_size, void* d_ws, size_t ws_size,
                              hipStream_t stream) {
  const float* x    = (const float*)d_in[0];
  // d_in[1] = causal mask (hardcoded)
  const float* Wqkv = (const float*)d_in[2];
  const float* bqkv = (const float*)d_in[3];
  const float* Wout = (const float*)d_in[4];
  const float* bout = (const float*)d_in[5];
  float* out = (float*)d_out;

  char* ws = (char*)d_ws;
  // workspace layout (96 MiB total, same footprint as round 2)
  unsigned short* Qh  = (unsigned short*)(ws);               // 8.39MB each
  unsigned short* Ql  = (unsigned short*)(ws + 8388608);
  unsigned short* Kh  = (unsigned short*)(ws + 16777216);
  unsigned short* Kl  = (unsigned short*)(ws + 25165824);
  unsigned short* Vth = (unsigned short*)(ws + 33554432);
  unsigned short* Vtl = (unsigned short*)(ws + 41943040);
  unsigned short* atthi = (unsigned short*)(ws + 50331648);
  unsigned short* attlo = (unsigned short*)(ws + 58720256);
  unsigned short* xhi = (unsigned short*)(ws + 67108864);
  unsigned short* xlo = (unsigned short*)(ws + 75497472);
  unsigned short* wqh = (unsigned short*)(ws + 83886080);
  unsigned short* wql = (unsigned short*)(ws + 90177536);
  unsigned short* woh = (unsigned short*)(ws + 96468992);
  unsigned short* wol = (unsigned short*)(ws + 98566144);

  const int M = Bb * Ss;  // 4096

  split_f32<<<(M * Dd / 8) / 256, 256, 0, stream>>>(x, xhi, xlo, M * Dd / 8);
  transpose_split_f32<<<dim3(3 * Dd / 32, Dd / 32), 256, 0, stream>>>(Wqkv, wqh, wql, Dd, 3 * Dd);
  transpose_split_f32<<<dim3(Dd / 32, Dd / 32), 256, 0, stream>>>(Wout, woh, wol, Dd, Dd);

  // 1) QKV projection, fused split + per-head scatter (Q scaled, Vt transposed)
  gemm_qkv<1024><<<dim3(3 * Dd / 128, M / 128), 256, 0, stream>>>(
      xhi, xlo, wqh, wql, bqkv, Qh, Ql, Kh, Kl, Vth, Vtl);

  // 2) MFMA causal flash attention -> split-bf16 att
  flash_attn_mfma<<<dim3(Ss / 128, Hh, Bb), 256, 0, stream>>>(
      Qh, Ql, Kh, Kl, Vth, Vtl, atthi, attlo);

  // 3) output projection
  gemm_split_bf16<1024><<<dim3(Dd / 128, M / 128), 256, 0, stream>>>(
      atthi, attlo, woh, wol, bout, out, Dd);
}

// Round 4
// 384.993 us; speedup vs baseline: 2.5730x; 1.0587x over previous
//
#include <hip/hip_runtime.h>
#include <math.h>

// Problem constants
constexpr int Bb = 2, Ss = 2048, Dd = 1024, Hh = 16, HDd = 64;

typedef __attribute__((ext_vector_type(8))) short bf16x8;     // MFMA A/B frag
typedef __attribute__((ext_vector_type(4))) float f32x4;      // MFMA C/D frag
typedef __attribute__((ext_vector_type(8))) unsigned short u16x8;
typedef __attribute__((ext_vector_type(4))) unsigned short u16x4;

__device__ __forceinline__ unsigned short bf16_rn(float f) {
  unsigned int u = __float_as_uint(f);
  u += 0x7fffu + ((u >> 16) & 1u);
  return (unsigned short)(u >> 16);
}
__device__ __forceinline__ float bf16_f(unsigned short h) {
  return __uint_as_float(((unsigned int)h) << 16);
}

// ---------------------------------------------------------------------------
// split fp32 array into hi/lo bf16 arrays
// ---------------------------------------------------------------------------
__global__ __launch_bounds__(256) void split_f32(
    const float* __restrict__ in, unsigned short* __restrict__ hi,
    unsigned short* __restrict__ lo, int n8) {
  int i = blockIdx.x * 256 + threadIdx.x;
  if (i >= n8) return;
  const float4* p = (const float4*)in + (size_t)i * 2;
  float4 a = p[0], b = p[1];
  float v[8] = {a.x, a.y, a.z, a.w, b.x, b.y, b.z, b.w};
  u16x8 h, l;
  #pragma unroll
  for (int j = 0; j < 8; j++) {
    unsigned short hb = bf16_rn(v[j]);
    h[j] = hb;
    l[j] = bf16_rn(v[j] - bf16_f(hb));
  }
  *(u16x8*)(hi + (size_t)i * 8) = h;
  *(u16x8*)(lo + (size_t)i * 8) = l;
}

// transpose W[K][N] -> Wt[N][K], split into hi/lo bf16
__global__ __launch_bounds__(256) void transpose_split_f32(
    const float* __restrict__ W, unsigned short* __restrict__ Thi,
    unsigned short* __restrict__ Tlo, int K, int N) {
  __shared__ float tile[32][33];
  int n0 = blockIdx.x * 32, k0 = blockIdx.y * 32;
  int t = threadIdx.x;
  #pragma unroll
  for (int p = 0; p < 4; p++) {
    int idx = t + p * 256;
    int kk = idx >> 5, nn = idx & 31;
    tile[kk][nn] = W[(size_t)(k0 + kk) * N + n0 + nn];
  }
  __syncthreads();
  #pragma unroll
  for (int p = 0; p < 4; p++) {
    int idx = t + p * 256;
    int nn = idx >> 5, kk = idx & 31;
    float v = tile[kk][nn];
    unsigned short hb = bf16_rn(v);
    size_t o = (size_t)(n0 + nn) * K + k0 + kk;
    Thi[o] = hb;
    Tlo[o] = bf16_rn(v - bf16_f(hb));
  }
}

// ---------------------------------------------------------------------------
typedef __attribute__((address_space(3))) unsigned int lds_u32;
typedef const __attribute__((address_space(1))) unsigned int glb_u32;
__device__ __forceinline__ void gload16(const void* g, void* l) {
  __builtin_amdgcn_global_load_lds((glb_u32*)g, (lds_u32*)l, 16, 0, 0);
}

// ---------------------------------------------------------------------------
// Split-bf16 MFMA GEMM core (m97 structure). A row-major hi/lo [M][K];
// B transposed hi/lo [N][K]. Unchanged from round 3 (verified).
// ---------------------------------------------------------------------------
#define GEMM_CORE(KD)                                                          \
  __shared__ unsigned short lds[4 * 4096];                                     \
  const int tid = threadIdx.x;                                                 \
  const int lane = tid & 63, wid = tid >> 6;                                   \
  const int m0 = blockIdx.y * 128, n0 = blockIdx.x * 128;                      \
  const int wrow = wid >> 1, wcol = wid & 1;                                   \
  const int lrow = lane & 15, g = lane >> 4;                                   \
  const int o0 = wid * 128 + lane, o1 = o0 + 64;                               \
  const int r0 = o0 >> 2, G0 = (o0 & 3) ^ ((r0 >> 1) & 3);                     \
  const int r1 = o1 >> 2, G1 = (o1 & 3) ^ ((r1 >> 1) & 3);                     \
  const unsigned short* sA0h = Ahi + (size_t)(m0 + r0) * KD + G0 * 8;          \
  const unsigned short* sA1h = Ahi + (size_t)(m0 + r1) * KD + G1 * 8;          \
  const unsigned short* sA0l = Alo + (size_t)(m0 + r0) * KD + G0 * 8;          \
  const unsigned short* sA1l = Alo + (size_t)(m0 + r1) * KD + G1 * 8;          \
  const unsigned short* sB0h = Bhi + (size_t)(n0 + r0) * KD + G0 * 8;          \
  const unsigned short* sB1h = Bhi + (size_t)(n0 + r1) * KD + G1 * 8;          \
  const unsigned short* sB0l = Blo + (size_t)(n0 + r0) * KD + G0 * 8;          \
  const unsigned short* sB1l = Blo + (size_t)(n0 + r1) * KD + G1 * 8;          \
  unsigned short* dA0h = lds + 0 + wid * 1024;                                 \
  unsigned short* dA1h = dA0h + 512;                                           \
  unsigned short* dA0l = lds + 4096 + wid * 1024;                              \
  unsigned short* dA1l = dA0l + 512;                                           \
  unsigned short* dB0h = lds + 8192 + wid * 1024;                              \
  unsigned short* dB1h = dB0h + 512;                                           \
  unsigned short* dB0l = lds + 12288 + wid * 1024;                             \
  unsigned short* dB1l = dB0l + 512;                                           \
  int offA[4], offB[4];                                                        \
  _Pragma("unroll")                                                            \
  for (int m = 0; m < 4; m++) {                                                \
    int row = wrow * 64 + m * 16 + lrow;                                       \
    offA[m] = row * 32 + ((g ^ ((row >> 1) & 3)) * 8);                         \
  }                                                                            \
  _Pragma("unroll")                                                            \
  for (int n = 0; n < 4; n++) {                                                \
    int row = wcol * 64 + n * 16 + lrow;                                       \
    offB[n] = row * 32 + ((g ^ ((row >> 1) & 3)) * 8);                         \
  }                                                                            \
  f32x4 acc[4][4];                                                             \
  _Pragma("unroll")                                                            \
  for (int m = 0; m < 4; m++)                                                  \
    _Pragma("unroll")                                                          \
    for (int n = 0; n < 4; n++) acc[m][n] = (f32x4){0.f, 0.f, 0.f, 0.f};       \
  for (int k0 = 0; k0 < KD; k0 += 32) {                                        \
    gload16(sA0h + k0, dA0h); gload16(sA1h + k0, dA1h);                        \
    gload16(sA0l + k0, dA0l); gload16(sA1l + k0, dA1l);                        \
    gload16(sB0h + k0, dB0h); gload16(sB1h + k0, dB1h);                        \
    gload16(sB0l + k0, dB0l); gload16(sB1l + k0, dB1l);                        \
    __syncthreads();                                                           \
    bf16x8 ah[4], al[4], bh[4], bl[4];                                         \
    _Pragma("unroll")                                                          \
    for (int m = 0; m < 4; m++) {                                              \
      ah[m] = *(const bf16x8*)(lds + 0 + offA[m]);                             \
      al[m] = *(const bf16x8*)(lds + 4096 + offA[m]);                          \
    }                                                                          \
    _Pragma("unroll")                                                          \
    for (int n = 0; n < 4; n++) {                                              \
      bh[n] = *(const bf16x8*)(lds + 8192 + offB[n]);                          \
      bl[n] = *(const bf16x8*)(lds + 12288 + offB[n]);                         \
    }                                                                          \
    _Pragma("unroll")                                                          \
    for (int m = 0; m < 4; m++)                                                \
      _Pragma("unroll")                                                        \
      for (int n = 0; n < 4; n++) {                                            \
        acc[m][n] = __builtin_amdgcn_mfma_f32_16x16x32_bf16(ah[m], bh[n], acc[m][n], 0, 0, 0); \
        acc[m][n] = __builtin_amdgcn_mfma_f32_16x16x32_bf16(ah[m], bl[n], acc[m][n], 0, 0, 0); \
        acc[m][n] = __builtin_amdgcn_mfma_f32_16x16x32_bf16(al[m], bh[n], acc[m][n], 0, 0, 0); \
      }                                                                        \
    __syncthreads();                                                           \
  }

// GEMM with plain f32 output (out-projection)
template<int KD>
__global__ __launch_bounds__(256) void gemm_split_bf16(
    const unsigned short* __restrict__ Ahi, const unsigned short* __restrict__ Alo,
    const unsigned short* __restrict__ Bhi, const unsigned short* __restrict__ Blo,
    const float* __restrict__ bias, float* __restrict__ C, int N)
{
  GEMM_CORE(KD)
  #pragma unroll
  for (int n = 0; n < 4; n++) {
    int gcol = n0 + wcol * 64 + n * 16 + lrow;
    float bv = bias[gcol];
    #pragma unroll
    for (int m = 0; m < 4; m++) {
      f32x4 a = acc[m][n];
      #pragma unroll
      for (int r = 0; r < 4; r++) {
        int grow = m0 + wrow * 64 + m * 16 + g * 4 + r;
        C[(size_t)grow * N + gcol] = a[r] + bv;
      }
    }
  }
}

// QKV GEMM: epilogue scatters into per-head split-bf16 Q/K/Vt arrays.
// Q pre-scaled by (1/sqrt(HD)) * log2(e) so softmax can use exp2 directly.
template<int KD>
__global__ __launch_bounds__(256) void gemm_qkv(
    const unsigned short* __restrict__ Ahi, const unsigned short* __restrict__ Alo,
    const unsigned short* __restrict__ Bhi, const unsigned short* __restrict__ Blo,
    const float* __restrict__ bias,
    unsigned short* __restrict__ Qh, unsigned short* __restrict__ Ql,
    unsigned short* __restrict__ Kh, unsigned short* __restrict__ Kl,
    unsigned short* __restrict__ Vth, unsigned short* __restrict__ Vtl)
{
  GEMM_CORE(KD)
  const int bidx = m0 >> 11;
  const int sbase = (m0 & 2047) + wrow * 64 + g * 4;
  #pragma unroll
  for (int n = 0; n < 4; n++) {
    int gcol = n0 + wcol * 64 + n * 16 + lrow;
    unsigned hh = (unsigned)gcol / 192u;
    int inner = gcol - (int)hh * 192;
    int part = inner >> 6;
    int d = inner & 63;
    float bv = bias[gcol];
    size_t base = (size_t)(bidx * 16 + (int)hh) * 131072;
    #pragma unroll
    for (int m = 0; m < 4; m++) {
      f32x4 a = acc[m][n];
      int s0 = sbase + m * 16;
      if (part == 0) {
        #pragma unroll
        for (int r = 0; r < 4; r++) {
          float v = (a[r] + bv) * 0.18033688011112042f;  // 0.125 * log2(e)
          unsigned short hi = bf16_rn(v);
          size_t ix = base + (size_t)(s0 + r) * 64 + d;
          Qh[ix] = hi; Ql[ix] = bf16_rn(v - bf16_f(hi));
        }
      } else if (part == 1) {
        #pragma unroll
        for (int r = 0; r < 4; r++) {
          float v = a[r] + bv;
          unsigned short hi = bf16_rn(v);
          size_t ix = base + (size_t)(s0 + r) * 64 + d;
          Kh[ix] = hi; Kl[ix] = bf16_rn(v - bf16_f(hi));
        }
      } else {
        u16x4 hv, lv;
        #pragma unroll
        for (int r = 0; r < 4; r++) {
          float v = a[r] + bv;
          hv[r] = bf16_rn(v);
          lv[r] = bf16_rn(v - bf16_f(hv[r]));
        }
        size_t ix = base + (size_t)d * 2048 + s0;
        *(u16x4*)(Vth + ix) = hv;
        *(u16x4*)(Vtl + ix) = lv;
      }
    }
  }
}

// ---------------------------------------------------------------------------
// MFMA flash attention, 2-phase double-buffered (T3-minimum):
//   prologue STAGE(0); loop { STAGE(t+1) -> buf^1; compute(t) on buf;
//   __syncthreads(); }  -- one barrier/tile, loads hidden under compute.
// Logits are in log2 domain (Q pre-scaled by log2e/8) -> exp2 softmax.
// ---------------------------------------------------------------------------
__global__ __launch_bounds__(256) void flash_attn_mfma(
    const unsigned short* __restrict__ Qh, const unsigned short* __restrict__ Ql,
    const unsigned short* __restrict__ Kh, const unsigned short* __restrict__ Kl,
    const unsigned short* __restrict__ Vth, const unsigned short* __restrict__ Vtl,
    unsigned short* __restrict__ atthi, unsigned short* __restrict__ attlo)
{
  const int qt = (int)gridDim.x - 1 - (int)blockIdx.x;   // big tiles first
  const int h = blockIdx.y, b = blockIdx.z;
  const int bh = b * Hh + h;
  const int q0 = qt * 128;
  const int tid = threadIdx.x, lane = tid & 63, wid = tid >> 6;
  const int q0w = q0 + wid * 32;
  const int lrow = lane & 15, lg = lane >> 4;

  __shared__ unsigned short KH[2][4096], KL[2][4096], VH[2][4096], VL[2][4096];
  __shared__ unsigned short Pbuf[4][2048];

  const size_t hb = (size_t)bh * 131072;
  const unsigned short* qhb = Qh + hb;
  const unsigned short* qlb = Ql + hb;
  const unsigned short* khb = Kh + hb;
  const unsigned short* klb = Kl + hb;
  const unsigned short* vhb = Vth + hb;
  const unsigned short* vlb = Vtl + hb;

  // Q fragments hoisted to registers (pre-scaled in GEMM epilogue)
  bf16x8 qfh[2][2], qfl[2][2];
  #pragma unroll
  for (int mi = 0; mi < 2; mi++)
    #pragma unroll
    for (int ks = 0; ks < 2; ks++) {
      int off = (q0w + mi * 16 + lrow) * 64 + ks * 32 + lg * 8;
      qfh[mi][ks] = *(const bf16x8*)(qhb + off);
      qfl[mi][ks] = *(const bf16x8*)(qlb + off);
    }

  // LDS fragment offsets (elements), swizzle g^(row&7)
  int offK[4][2], offP[2][2];
  #pragma unroll
  for (int ci = 0; ci < 4; ci++)
    #pragma unroll
    for (int ks = 0; ks < 2; ks++) {
      int row = ci * 16 + lrow;
      offK[ci][ks] = row * 64 + (((ks * 4 + lg) ^ (row & 7)) * 8);
    }
  #pragma unroll
  for (int mi = 0; mi < 2; mi++)
    #pragma unroll
    for (int ks = 0; ks < 2; ks++) {
      int row = mi * 16 + lrow;
      offP[mi][ks] = row * 64 + (((ks * 4 + lg) ^ (row & 7)) * 8);
    }

  // staging: thread covers granules o=tid and o=tid+256 of each [64][64] tile
  const int o0 = tid, o1 = tid + 256;
  const int sr0 = o0 >> 3, sg0 = ((o0 & 7) ^ (sr0 & 7)) * 8;
  const int sr1 = o1 >> 3, sg1 = ((o1 & 7) ^ (sr1 & 7)) * 8;

  float m_[2][4], l_[2][4];
  f32x4 oacc[2][4];
  #pragma unroll
  for (int mi = 0; mi < 2; mi++)
    #pragma unroll
    for (int r = 0; r < 4; r++) { m_[mi][r] = -INFINITY; l_[mi][r] = 0.f; }
  #pragma unroll
  for (int mi = 0; mi < 2; mi++)
    #pragma unroll
    for (int di = 0; di < 4; di++) oacc[mi][di] = (f32x4){0.f, 0.f, 0.f, 0.f};

  unsigned short* Pw = Pbuf[wid];
  const int nt = (q0 + 128) >> 6;   // kv tiles

  // prologue: stage tile 0 into buffer 0
  {
    gload16(khb + (size_t)sr0 * 64 + sg0, KH[0] + wid * 512);
    gload16(khb + (size_t)sr1 * 64 + sg1, KH[0] + 2048 + wid * 512);
    gload16(klb + (size_t)sr0 * 64 + sg0, KL[0] + wid * 512);
    gload16(klb + (size_t)sr1 * 64 + sg1, KL[0] + 2048 + wid * 512);
    gload16(vhb + (size_t)sr0 * 2048 + sg0, VH[0] + wid * 512);
    gload16(vhb + (size_t)sr1 * 2048 + sg1, VH[0] + 2048 + wid * 512);
    gload16(vlb + (size_t)sr0 * 2048 + sg0, VL[0] + wid * 512);
    gload16(vlb + (size_t)sr1 * 2048 + sg1, VL[0] + 2048 + wid * 512);
  }
  __syncthreads();

  for (int t = 0; t < nt; ++t) {
    const int kv0 = t * 64;
    // prefetch next tile into the other buffer (overlaps with compute below)
    if (t + 1 < nt) {
      const int nb = (t + 1) & 1;
      const int nk = kv0 + 64;
      gload16(khb + (size_t)(nk + sr0) * 64 + sg0, KH[nb] + wid * 512);
      gload16(khb + (size_t)(nk + sr1) * 64 + sg1, KH[nb] + 2048 + wid * 512);
      gload16(klb + (size_t)(nk + sr0) * 64 + sg0, KL[nb] + wid * 512);
      gload16(klb + (size_t)(nk + sr1) * 64 + sg1, KL[nb] + 2048 + wid * 512);
      gload16(vhb + (size_t)sr0 * 2048 + nk + sg0, VH[nb] + wid * 512);
      gload16(vhb + (size_t)sr1 * 2048 + nk + sg1, VH[nb] + 2048 + wid * 512);
      gload16(vlb + (size_t)sr0 * 2048 + nk + sg0, VL[nb] + wid * 512);
      gload16(vlb + (size_t)sr1 * 2048 + nk + sg1, VL[nb] + 2048 + wid * 512);
    }

    if (kv0 <= q0w + 31) {            // wave-uniform: skip fully-masked tiles
      const int cb = t & 1;
      const unsigned short* KHc = KH[cb];
      const unsigned short* KLc = KL[cb];
      const unsigned short* VHc = VH[cb];
      const unsigned short* VLc = VL[cb];

      // S = Q K^T (3-term split)
      f32x4 sf[2][4];
      #pragma unroll
      for (int mi = 0; mi < 2; mi++)
        #pragma unroll
        for (int ci = 0; ci < 4; ci++) sf[mi][ci] = (f32x4){0.f, 0.f, 0.f, 0.f};
      __builtin_amdgcn_s_setprio(1);
      #pragma unroll
      for (int ci = 0; ci < 4; ci++) {
        bf16x8 kh0 = *(const bf16x8*)(KHc + offK[ci][0]);
        bf16x8 kh1 = *(const bf16x8*)(KHc + offK[ci][1]);
        bf16x8 kl0 = *(const bf16x8*)(KLc + offK[ci][0]);
        bf16x8 kl1 = *(const bf16x8*)(KLc + offK[ci][1]);
        #pragma unroll
        for (int mi = 0; mi < 2; mi++) {
          f32x4 s = sf[mi][ci];
          s = __builtin_amdgcn_mfma_f32_16x16x32_bf16(qfh[mi][0], kh0, s, 0, 0, 0);
          s = __builtin_amdgcn_mfma_f32_16x16x32_bf16(qfh[mi][1], kh1, s, 0, 0, 0);
          s = __builtin_amdgcn_mfma_f32_16x16x32_bf16(qfh[mi][0], kl0, s, 0, 0, 0);
          s = __builtin_amdgcn_mfma_f32_16x16x32_bf16(qfh[mi][1], kl1, s, 0, 0, 0);
          s = __builtin_amdgcn_mfma_f32_16x16x32_bf16(qfl[mi][0], kh0, s, 0, 0, 0);
          s = __builtin_amdgcn_mfma_f32_16x16x32_bf16(qfl[mi][1], kh1, s, 0, 0, 0);
          sf[mi][ci] = s;
        }
      }
      __builtin_amdgcn_s_setprio(0);

      // causal mask on straddling tiles
      if (kv0 + 63 > q0w) {
        #pragma unroll
        for (int mi = 0; mi < 2; mi++)
          #pragma unroll
          for (int ci = 0; ci < 4; ci++)
            #pragma unroll
            for (int r = 0; r < 4; r++) {
              int q = q0w + mi * 16 + lg * 4 + r;
              int kv = kv0 + ci * 16 + lrow;
              if (kv > q) sf[mi][ci][r] = -1e30f;
            }
      }

      // online softmax in log2 domain (p = 2^(s-m))
      #pragma unroll
      for (int mi = 0; mi < 2; mi++)
        #pragma unroll
        for (int r = 0; r < 4; r++) {
          float mx = fmaxf(fmaxf(sf[mi][0][r], sf[mi][1][r]),
                           fmaxf(sf[mi][2][r], sf[mi][3][r]));
          mx = fmaxf(mx, __shfl_xor(mx, 1));
          mx = fmaxf(mx, __shfl_xor(mx, 2));
          mx = fmaxf(mx, __shfl_xor(mx, 4));
          mx = fmaxf(mx, __shfl_xor(mx, 8));
          float mn = fmaxf(m_[mi][r], mx);
          float alpha = __builtin_amdgcn_exp2f(m_[mi][r] - mn);
          m_[mi][r] = mn;
          float rs = 0.f;
          #pragma unroll
          for (int ci = 0; ci < 4; ci++) {
            float p = __builtin_amdgcn_exp2f(sf[mi][ci][r] - mn);
            sf[mi][ci][r] = p;
            rs += p;
          }
          rs += __shfl_xor(rs, 1);
          rs += __shfl_xor(rs, 2);
          rs += __shfl_xor(rs, 4);
          rs += __shfl_xor(rs, 8);
          l_[mi][r] = l_[mi][r] * alpha + rs;
          #pragma unroll
          for (int di = 0; di < 4; di++) oacc[mi][di][r] *= alpha;
        }

      // P -> wave-private LDS as bf16 (swizzled); no barrier needed
      #pragma unroll
      for (int mi = 0; mi < 2; mi++)
        #pragma unroll
        for (int ci = 0; ci < 4; ci++) {
          int colb = ci * 16 + lrow;
          int gcol = colb >> 3, crem = colb & 7;
          #pragma unroll
          for (int r = 0; r < 4; r++) {
            int rr = mi * 16 + lg * 4 + r;
            Pw[rr * 64 + ((gcol ^ (rr & 7)) * 8) + crem] = bf16_rn(sf[mi][ci][r]);
          }
        }

      // O += P (Vh + Vl)
      bf16x8 pa[2][2];
      #pragma unroll
      for (int mi = 0; mi < 2; mi++)
        #pragma unroll
        for (int ks = 0; ks < 2; ks++)
          pa[mi][ks] = *(const bf16x8*)(Pw + offP[mi][ks]);
      __builtin_amdgcn_s_setprio(1);
      #pragma unroll
      for (int di = 0; di < 4; di++) {
        bf16x8 vh0 = *(const bf16x8*)(VHc + offK[di][0]);
        bf16x8 vh1 = *(const bf16x8*)(VHc + offK[di][1]);
        bf16x8 vl0 = *(const bf16x8*)(VLc + offK[di][0]);
        bf16x8 vl1 = *(const bf16x8*)(VLc + offK[di][1]);
        #pragma unroll
        for (int mi = 0; mi < 2; mi++) {
          f32x4 o = oacc[mi][di];
          o = __builtin_amdgcn_mfma_f32_16x16x32_bf16(pa[mi][0], vh0, o, 0, 0, 0);
          o = __builtin_amdgcn_mfma_f32_16x16x32_bf16(pa[mi][1], vh1, o, 0, 0, 0);
          o = __builtin_amdgcn_mfma_f32_16x16x32_bf16(pa[mi][0], vl0, o, 0, 0, 0);
          o = __builtin_amdgcn_mfma_f32_16x16x32_bf16(pa[mi][1], vl1, o, 0, 0, 0);
          oacc[mi][di] = o;
        }
      }
      __builtin_amdgcn_s_setprio(0);
    }
    __syncthreads();   // drains vmcnt: next buffer ready; cur buffer reusable
  }

  // epilogue: normalize, write split-bf16 att [B*S][1024]
  #pragma unroll
  for (int mi = 0; mi < 2; mi++) {
    float inv[4];
    #pragma unroll
    for (int r = 0; r < 4; r++) inv[r] = 1.f / l_[mi][r];
    #pragma unroll
    for (int di = 0; di < 4; di++) {
      f32x4 o = oacc[mi][di];
      #pragma unroll
      for (int r = 0; r < 4; r++) {
        float v = o[r] * inv[r];
        int srow = q0w + mi * 16 + lg * 4 + r;
        size_t idx = ((size_t)b * Ss + srow) * 1024 + h * 64 + di * 16 + lrow;
        unsigned short hi = bf16_rn(v);
        atthi[idx] = hi;
        attlo[idx] = bf16_rn(v - bf16_f(hi));
      }
    }
  }
}

// ---------------------------------------------------------------------------
extern "C" void kernel_launch(void* const* d_in, const int* in_sizes, int n_in,
                              void* d_out, int out_size, void* d_ws, size_t ws_size,
                              hipStream_t stream) {
  const float* x    = (const float*)d_in[0];
  // d_in[1] = causal mask (hardcoded)
  const float* Wqkv = (const float*)d_in[2];
  const float* bqkv = (const float*)d_in[3];
  const float* Wout = (const float*)d_in[4];
  const float* bout = (const float*)d_in[5];
  float* out = (float*)d_out;

  char* ws = (char*)d_ws;
  unsigned short* Qh  = (unsigned short*)(ws);
  unsigned short* Ql  = (unsigned short*)(ws + 8388608);
  unsigned short* Kh  = (unsigned short*)(ws + 16777216);
  unsigned short* Kl  = (unsigned short*)(ws + 25165824);
  unsigned short* Vth = (unsigned short*)(ws + 33554432);
  unsigned short* Vtl = (unsigned short*)(ws + 41943040);
  unsigned short* atthi = (unsigned short*)(ws + 50331648);
  unsigned short* attlo = (unsigned short*)(ws + 58720256);
  unsigned short* xhi = (unsigned short*)(ws + 67108864);
  unsigned short* xlo = (unsigned short*)(ws + 75497472);
  unsigned short* wqh = (unsigned short*)(ws + 83886080);
  unsigned short* wql = (unsigned short*)(ws + 90177536);
  unsigned short* woh = (unsigned short*)(ws + 96468992);
  unsigned short* wol = (unsigned short*)(ws + 98566144);

  const int M = Bb * Ss;  // 4096

  split_f32<<<(M * Dd / 8) / 256, 256, 0, stream>>>(x, xhi, xlo, M * Dd / 8);
  transpose_split_f32<<<dim3(3 * Dd / 32, Dd / 32), 256, 0, stream>>>(Wqkv, wqh, wql, Dd, 3 * Dd);
  transpose_split_f32<<<dim3(Dd / 32, Dd / 32), 256, 0, stream>>>(Wout, woh, wol, Dd, Dd);

  // 1) QKV projection, fused split + per-head scatter (Q log2-scaled, Vt transposed)
  gemm_qkv<1024><<<dim3(3 * Dd / 128, M / 128), 256, 0, stream>>>(
      xhi, xlo, wqh, wql, bqkv, Qh, Ql, Kh, Kl, Vth, Vtl);

  // 2) MFMA causal flash attention (2-phase dbuf) -> split-bf16 att
  flash_attn_mfma<<<dim3(Ss / 128, Hh, Bb), 256, 0, stream>>>(
      Qh, Ql, Kh, Kl, Vth, Vtl, atthi, attlo);

  // 3) output projection
  gemm_split_bf16<1024><<<dim3(Dd / 128, M / 128), 256, 0, stream>>>(
      atthi, attlo, woh, wol, bout, out, Dd);
}

// Round 5
// 355.530 us; speedup vs baseline: 2.7863x; 1.0829x over previous
//
#include <hip/hip_runtime.h>
#include <math.h>

// Problem constants
constexpr int Bb = 2, Ss = 2048, Dd = 1024, Hh = 16, HDd = 64;

typedef __attribute__((ext_vector_type(8))) short bf16x8;     // MFMA A/B frag
typedef __attribute__((ext_vector_type(4))) float f32x4;      // MFMA C/D frag
typedef __attribute__((ext_vector_type(8))) unsigned short u16x8;
typedef __attribute__((ext_vector_type(4))) unsigned short u16x4;

__device__ __forceinline__ unsigned short bf16_rn(float f) {
  unsigned int u = __float_as_uint(f);
  u += 0x7fffu + ((u >> 16) & 1u);
  return (unsigned short)(u >> 16);
}
__device__ __forceinline__ float bf16_f(unsigned short h) {
  return __uint_as_float(((unsigned int)h) << 16);
}

// ---------------------------------------------------------------------------
// split fp32 array into hi/lo bf16 arrays
// ---------------------------------------------------------------------------
__global__ __launch_bounds__(256) void split_f32(
    const float* __restrict__ in, unsigned short* __restrict__ hi,
    unsigned short* __restrict__ lo, int n8) {
  int i = blockIdx.x * 256 + threadIdx.x;
  if (i >= n8) return;
  const float4* p = (const float4*)in + (size_t)i * 2;
  float4 a = p[0], b = p[1];
  float v[8] = {a.x, a.y, a.z, a.w, b.x, b.y, b.z, b.w};
  u16x8 h, l;
  #pragma unroll
  for (int j = 0; j < 8; j++) {
    unsigned short hb = bf16_rn(v[j]);
    h[j] = hb;
    l[j] = bf16_rn(v[j] - bf16_f(hb));
  }
  *(u16x8*)(hi + (size_t)i * 8) = h;
  *(u16x8*)(lo + (size_t)i * 8) = l;
}

// transpose W[K][N] -> Wt[N][K], split into hi/lo bf16
__global__ __launch_bounds__(256) void transpose_split_f32(
    const float* __restrict__ W, unsigned short* __restrict__ Thi,
    unsigned short* __restrict__ Tlo, int K, int N) {
  __shared__ float tile[32][33];
  int n0 = blockIdx.x * 32, k0 = blockIdx.y * 32;
  int t = threadIdx.x;
  #pragma unroll
  for (int p = 0; p < 4; p++) {
    int idx = t + p * 256;
    int kk = idx >> 5, nn = idx & 31;
    tile[kk][nn] = W[(size_t)(k0 + kk) * N + n0 + nn];
  }
  __syncthreads();
  #pragma unroll
  for (int p = 0; p < 4; p++) {
    int idx = t + p * 256;
    int nn = idx >> 5, kk = idx & 31;
    float v = tile[kk][nn];
    unsigned short hb = bf16_rn(v);
    size_t o = (size_t)(n0 + nn) * K + k0 + kk;
    Thi[o] = hb;
    Tlo[o] = bf16_rn(v - bf16_f(hb));
  }
}

// ---------------------------------------------------------------------------
typedef __attribute__((address_space(3))) unsigned int lds_u32;
typedef const __attribute__((address_space(1))) unsigned int glb_u32;
__device__ __forceinline__ void gload16(const void* g, void* l) {
  __builtin_amdgcn_global_load_lds((glb_u32*)g, (lds_u32*)l, 16, 0, 0);
}

// ---------------------------------------------------------------------------
// Split-bf16 MFMA GEMM core (m97 structure). A row-major hi/lo [M][K];
// B transposed hi/lo [N][K]. Verified rounds 2-4.
// ---------------------------------------------------------------------------
#define GEMM_CORE(KD)                                                          \
  __shared__ unsigned short lds[4 * 4096];                                     \
  const int tid = threadIdx.x;                                                 \
  const int lane = tid & 63, wid = tid >> 6;                                   \
  const int m0 = blockIdx.y * 128, n0 = blockIdx.x * 128;                      \
  const int wrow = wid >> 1, wcol = wid & 1;                                   \
  const int lrow = lane & 15, g = lane >> 4;                                   \
  const int o0 = wid * 128 + lane, o1 = o0 + 64;                               \
  const int r0 = o0 >> 2, G0 = (o0 & 3) ^ ((r0 >> 1) & 3);                     \
  const int r1 = o1 >> 2, G1 = (o1 & 3) ^ ((r1 >> 1) & 3);                     \
  const unsigned short* sA0h = Ahi + (size_t)(m0 + r0) * KD + G0 * 8;          \
  const unsigned short* sA1h = Ahi + (size_t)(m0 + r1) * KD + G1 * 8;          \
  const unsigned short* sA0l = Alo + (size_t)(m0 + r0) * KD + G0 * 8;          \
  const unsigned short* sA1l = Alo + (size_t)(m0 + r1) * KD + G1 * 8;          \
  const unsigned short* sB0h = Bhi + (size_t)(n0 + r0) * KD + G0 * 8;          \
  const unsigned short* sB1h = Bhi + (size_t)(n0 + r1) * KD + G1 * 8;          \
  const unsigned short* sB0l = Blo + (size_t)(n0 + r0) * KD + G0 * 8;          \
  const unsigned short* sB1l = Blo + (size_t)(n0 + r1) * KD + G1 * 8;          \
  unsigned short* dA0h = lds + 0 + wid * 1024;                                 \
  unsigned short* dA1h = dA0h + 512;                                           \
  unsigned short* dA0l = lds + 4096 + wid * 1024;                              \
  unsigned short* dA1l = dA0l + 512;                                           \
  unsigned short* dB0h = lds + 8192 + wid * 1024;                              \
  unsigned short* dB1h = dB0h + 512;                                           \
  unsigned short* dB0l = lds + 12288 + wid * 1024;                             \
  unsigned short* dB1l = dB0l + 512;                                           \
  int offA[4], offB[4];                                                        \
  _Pragma("unroll")                                                            \
  for (int m = 0; m < 4; m++) {                                                \
    int row = wrow * 64 + m * 16 + lrow;                                       \
    offA[m] = row * 32 + ((g ^ ((row >> 1) & 3)) * 8);                         \
  }                                                                            \
  _Pragma("unroll")                                                            \
  for (int n = 0; n < 4; n++) {                                                \
    int row = wcol * 64 + n * 16 + lrow;                                       \
    offB[n] = row * 32 + ((g ^ ((row >> 1) & 3)) * 8);                         \
  }                                                                            \
  f32x4 acc[4][4];                                                             \
  _Pragma("unroll")                                                            \
  for (int m = 0; m < 4; m++)                                                  \
    _Pragma("unroll")                                                          \
    for (int n = 0; n < 4; n++) acc[m][n] = (f32x4){0.f, 0.f, 0.f, 0.f};       \
  for (int k0 = 0; k0 < KD; k0 += 32) {                                        \
    gload16(sA0h + k0, dA0h); gload16(sA1h + k0, dA1h);                        \
    gload16(sA0l + k0, dA0l); gload16(sA1l + k0, dA1l);                        \
    gload16(sB0h + k0, dB0h); gload16(sB1h + k0, dB1h);                        \
    gload16(sB0l + k0, dB0l); gload16(sB1l + k0, dB1l);                        \
    __syncthreads();                                                           \
    bf16x8 ah[4], al[4], bh[4], bl[4];                                         \
    _Pragma("unroll")                                                          \
    for (int m = 0; m < 4; m++) {                                              \
      ah[m] = *(const bf16x8*)(lds + 0 + offA[m]);                             \
      al[m] = *(const bf16x8*)(lds + 4096 + offA[m]);                          \
    }                                                                          \
    _Pragma("unroll")                                                          \
    for (int n = 0; n < 4; n++) {                                              \
      bh[n] = *(const bf16x8*)(lds + 8192 + offB[n]);                          \
      bl[n] = *(const bf16x8*)(lds + 12288 + offB[n]);                         \
    }                                                                          \
    _Pragma("unroll")                                                          \
    for (int m = 0; m < 4; m++)                                                \
      _Pragma("unroll")                                                        \
      for (int n = 0; n < 4; n++) {                                            \
        acc[m][n] = __builtin_amdgcn_mfma_f32_16x16x32_bf16(ah[m], bh[n], acc[m][n], 0, 0, 0); \
        acc[m][n] = __builtin_amdgcn_mfma_f32_16x16x32_bf16(ah[m], bl[n], acc[m][n], 0, 0, 0); \
        acc[m][n] = __builtin_amdgcn_mfma_f32_16x16x32_bf16(al[m], bh[n], acc[m][n], 0, 0, 0); \
      }                                                                        \
    __syncthreads();                                                           \
  }

// GEMM with plain f32 output (out-projection)
template<int KD>
__global__ __launch_bounds__(256) void gemm_split_bf16(
    const unsigned short* __restrict__ Ahi, const unsigned short* __restrict__ Alo,
    const unsigned short* __restrict__ Bhi, const unsigned short* __restrict__ Blo,
    const float* __restrict__ bias, float* __restrict__ C, int N)
{
  GEMM_CORE(KD)
  #pragma unroll
  for (int n = 0; n < 4; n++) {
    int gcol = n0 + wcol * 64 + n * 16 + lrow;
    float bv = bias[gcol];
    #pragma unroll
    for (int m = 0; m < 4; m++) {
      f32x4 a = acc[m][n];
      #pragma unroll
      for (int r = 0; r < 4; r++) {
        int grow = m0 + wrow * 64 + m * 16 + g * 4 + r;
        C[(size_t)grow * N + gcol] = a[r] + bv;
      }
    }
  }
}

// QKV GEMM: epilogue scatters into per-head split-bf16 Q/K/Vt arrays.
// Q pre-scaled by (1/sqrt(HD)) * log2(e) so softmax can use exp2 directly.
template<int KD>
__global__ __launch_bounds__(256) void gemm_qkv(
    const unsigned short* __restrict__ Ahi, const unsigned short* __restrict__ Alo,
    const unsigned short* __restrict__ Bhi, const unsigned short* __restrict__ Blo,
    const float* __restrict__ bias,
    unsigned short* __restrict__ Qh, unsigned short* __restrict__ Ql,
    unsigned short* __restrict__ Kh, unsigned short* __restrict__ Kl,
    unsigned short* __restrict__ Vth, unsigned short* __restrict__ Vtl)
{
  GEMM_CORE(KD)
  const int bidx = m0 >> 11;
  const int sbase = (m0 & 2047) + wrow * 64 + g * 4;
  #pragma unroll
  for (int n = 0; n < 4; n++) {
    int gcol = n0 + wcol * 64 + n * 16 + lrow;
    unsigned hh = (unsigned)gcol / 192u;
    int inner = gcol - (int)hh * 192;
    int part = inner >> 6;
    int d = inner & 63;
    float bv = bias[gcol];
    size_t base = (size_t)(bidx * 16 + (int)hh) * 131072;
    #pragma unroll
    for (int m = 0; m < 4; m++) {
      f32x4 a = acc[m][n];
      int s0 = sbase + m * 16;
      if (part == 0) {
        #pragma unroll
        for (int r = 0; r < 4; r++) {
          float v = (a[r] + bv) * 0.18033688011112042f;  // 0.125 * log2(e)
          unsigned short hi = bf16_rn(v);
          size_t ix = base + (size_t)(s0 + r) * 64 + d;
          Qh[ix] = hi; Ql[ix] = bf16_rn(v - bf16_f(hi));
        }
      } else if (part == 1) {
        #pragma unroll
        for (int r = 0; r < 4; r++) {
          float v = a[r] + bv;
          unsigned short hi = bf16_rn(v);
          size_t ix = base + (size_t)(s0 + r) * 64 + d;
          Kh[ix] = hi; Kl[ix] = bf16_rn(v - bf16_f(hi));
        }
      } else {
        u16x4 hv, lv;
        #pragma unroll
        for (int r = 0; r < 4; r++) {
          float v = a[r] + bv;
          hv[r] = bf16_rn(v);
          lv[r] = bf16_rn(v - bf16_f(hv[r]));
        }
        size_t ix = base + (size_t)d * 2048 + s0;
        *(u16x4*)(Vth + ix) = hv;
        *(u16x4*)(Vtl + ix) = lv;
      }
    }
  }
}

// ---------------------------------------------------------------------------
// MFMA flash attention, causal-balanced pairing:
// block(pidx,h,b) = q-tiles {pidx, 15-pidx}; 8 waves x 32 rows (512 thr).
// Waves 0-3 -> low tile, 4-7 -> high tile; ONE shared KV sweep serves both.
// Per-block work is a constant 34 wave-tile-units -> perfect CU balance.
// 2-phase dbuf; exp2-domain softmax (Q pre-scaled by log2e/8).
// ---------------------------------------------------------------------------
__global__ __launch_bounds__(512) void flash_attn_mfma(
    const unsigned short* __restrict__ Qh, const unsigned short* __restrict__ Ql,
    const unsigned short* __restrict__ Kh, const unsigned short* __restrict__ Kl,
    const unsigned short* __restrict__ Vth, const unsigned short* __restrict__ Vtl,
    unsigned short* __restrict__ atthi, unsigned short* __restrict__ attlo)
{
  const int pidx = blockIdx.x;                 // 0..7
  const int h = blockIdx.y, b = blockIdx.z;
  const int bh = b * Hh + h;
  const int NT = Ss / 128;                     // 16 q-tiles
  const int qtA = pidx, qtB = NT - 1 - pidx;   // paired q-tiles
  const int tid = threadIdx.x, lane = tid & 63, wid = tid >> 6;
  const int q0w = (wid < 4) ? (qtA * 128 + wid * 32)
                            : (qtB * 128 + (wid - 4) * 32);
  const int lrow = lane & 15, lg = lane >> 4;

  __shared__ unsigned short KH[2][4096], KL[2][4096], VH[2][4096], VL[2][4096];
  __shared__ unsigned short Pbuf[8][2048];

  const size_t hb = (size_t)bh * 131072;
  const unsigned short* qhb = Qh + hb;
  const unsigned short* qlb = Ql + hb;
  const unsigned short* khb = Kh + hb;
  const unsigned short* klb = Kl + hb;
  const unsigned short* vhb = Vth + hb;
  const unsigned short* vlb = Vtl + hb;

  // Q fragments hoisted to registers (pre-scaled in GEMM epilogue)
  bf16x8 qfh[2][2], qfl[2][2];
  #pragma unroll
  for (int mi = 0; mi < 2; mi++)
    #pragma unroll
    for (int ks = 0; ks < 2; ks++) {
      int off = (q0w + mi * 16 + lrow) * 64 + ks * 32 + lg * 8;
      qfh[mi][ks] = *(const bf16x8*)(qhb + off);
      qfl[mi][ks] = *(const bf16x8*)(qlb + off);
    }

  // LDS fragment offsets (elements), swizzle g^(row&7)
  int offK[4][2], offP[2][2];
  #pragma unroll
  for (int ci = 0; ci < 4; ci++)
    #pragma unroll
    for (int ks = 0; ks < 2; ks++) {
      int row = ci * 16 + lrow;
      offK[ci][ks] = row * 64 + (((ks * 4 + lg) ^ (row & 7)) * 8);
    }
  #pragma unroll
  for (int mi = 0; mi < 2; mi++)
    #pragma unroll
    for (int ks = 0; ks < 2; ks++) {
      int row = mi * 16 + lrow;
      offP[mi][ks] = row * 64 + (((ks * 4 + lg) ^ (row & 7)) * 8);
    }

  // staging: 512 threads x 1 granule per array per tile (granule id = tid)
  const int sr = tid >> 3, sg = ((tid & 7) ^ ((tid >> 3) & 7)) * 8;

  float m_[2][4], l_[2][4];
  f32x4 oacc[2][4];
  #pragma unroll
  for (int mi = 0; mi < 2; mi++)
    #pragma unroll
    for (int r = 0; r < 4; r++) { m_[mi][r] = -INFINITY; l_[mi][r] = 0.f; }
  #pragma unroll
  for (int mi = 0; mi < 2; mi++)
    #pragma unroll
    for (int di = 0; di < 4; di++) oacc[mi][di] = (f32x4){0.f, 0.f, 0.f, 0.f};

  unsigned short* Pw = Pbuf[wid];
  const int nt = 2 * (qtB + 1);   // kv tiles for the pair (high tile dominates)

  // prologue: stage tile 0 into buffer 0 (4 gloads/thread)
  gload16(khb + (size_t)sr * 64 + sg, KH[0] + wid * 512);
  gload16(klb + (size_t)sr * 64 + sg, KL[0] + wid * 512);
  gload16(vhb + (size_t)sr * 2048 + sg, VH[0] + wid * 512);
  gload16(vlb + (size_t)sr * 2048 + sg, VL[0] + wid * 512);
  __syncthreads();

  for (int t = 0; t < nt; ++t) {
    const int kv0 = t * 64;
    // prefetch next tile into the other buffer (overlaps with compute below)
    if (t + 1 < nt) {
      const int nb = (t + 1) & 1;
      const int nk = kv0 + 64;
      gload16(khb + (size_t)(nk + sr) * 64 + sg, KH[nb] + wid * 512);
      gload16(klb + (size_t)(nk + sr) * 64 + sg, KL[nb] + wid * 512);
      gload16(vhb + (size_t)sr * 2048 + nk + sg, VH[nb] + wid * 512);
      gload16(vlb + (size_t)sr * 2048 + nk + sg, VL[nb] + wid * 512);
    }

    if (kv0 <= q0w + 31) {            // wave-uniform: skip fully-masked tiles
      const int cb = t & 1;
      const unsigned short* KHc = KH[cb];
      const unsigned short* KLc = KL[cb];
      const unsigned short* VHc = VH[cb];
      const unsigned short* VLc = VL[cb];

      // S = Q K^T (3-term split)
      f32x4 sf[2][4];
      #pragma unroll
      for (int mi = 0; mi < 2; mi++)
        #pragma unroll
        for (int ci = 0; ci < 4; ci++) sf[mi][ci] = (f32x4){0.f, 0.f, 0.f, 0.f};
      __builtin_amdgcn_s_setprio(1);
      #pragma unroll
      for (int ci = 0; ci < 4; ci++) {
        bf16x8 kh0 = *(const bf16x8*)(KHc + offK[ci][0]);
        bf16x8 kh1 = *(const bf16x8*)(KHc + offK[ci][1]);
        bf16x8 kl0 = *(const bf16x8*)(KLc + offK[ci][0]);
        bf16x8 kl1 = *(const bf16x8*)(KLc + offK[ci][1]);
        #pragma unroll
        for (int mi = 0; mi < 2; mi++) {
          f32x4 s = sf[mi][ci];
          s = __builtin_amdgcn_mfma_f32_16x16x32_bf16(qfh[mi][0], kh0, s, 0, 0, 0);
          s = __builtin_amdgcn_mfma_f32_16x16x32_bf16(qfh[mi][1], kh1, s, 0, 0, 0);
          s = __builtin_amdgcn_mfma_f32_16x16x32_bf16(qfh[mi][0], kl0, s, 0, 0, 0);
          s = __builtin_amdgcn_mfma_f32_16x16x32_bf16(qfh[mi][1], kl1, s, 0, 0, 0);
          s = __builtin_amdgcn_mfma_f32_16x16x32_bf16(qfl[mi][0], kh0, s, 0, 0, 0);
          s = __builtin_amdgcn_mfma_f32_16x16x32_bf16(qfl[mi][1], kh1, s, 0, 0, 0);
          sf[mi][ci] = s;
        }
      }
      __builtin_amdgcn_s_setprio(0);

      // causal mask on straddling tiles
      if (kv0 + 63 > q0w) {
        #pragma unroll
        for (int mi = 0; mi < 2; mi++)
          #pragma unroll
          for (int ci = 0; ci < 4; ci++)
            #pragma unroll
            for (int r = 0; r < 4; r++) {
              int q = q0w + mi * 16 + lg * 4 + r;
              int kv = kv0 + ci * 16 + lrow;
              if (kv > q) sf[mi][ci][r] = -1e30f;
            }
      }

      // online softmax in log2 domain (p = 2^(s-m))
      #pragma unroll
      for (int mi = 0; mi < 2; mi++)
        #pragma unroll
        for (int r = 0; r < 4; r++) {
          float mx = fmaxf(fmaxf(sf[mi][0][r], sf[mi][1][r]),
                           fmaxf(sf[mi][2][r], sf[mi][3][r]));
          mx = fmaxf(mx, __shfl_xor(mx, 1));
          mx = fmaxf(mx, __shfl_xor(mx, 2));
          mx = fmaxf(mx, __shfl_xor(mx, 4));
          mx = fmaxf(mx, __shfl_xor(mx, 8));
          float mn = fmaxf(m_[mi][r], mx);
          float alpha = __builtin_amdgcn_exp2f(m_[mi][r] - mn);
          m_[mi][r] = mn;
          float rs = 0.f;
          #pragma unroll
          for (int ci = 0; ci < 4; ci++) {
            float p = __builtin_amdgcn_exp2f(sf[mi][ci][r] - mn);
            sf[mi][ci][r] = p;
            rs += p;
          }
          rs += __shfl_xor(rs, 1);
          rs += __shfl_xor(rs, 2);
          rs += __shfl_xor(rs, 4);
          rs += __shfl_xor(rs, 8);
          l_[mi][r] = l_[mi][r] * alpha + rs;
          #pragma unroll
          for (int di = 0; di < 4; di++) oacc[mi][di][r] *= alpha;
        }

      // P -> wave-private LDS as bf16 (swizzled); no barrier needed
      #pragma unroll
      for (int mi = 0; mi < 2; mi++)
        #pragma unroll
        for (int ci = 0; ci < 4; ci++) {
          int colb = ci * 16 + lrow;
          int gcol = colb >> 3, crem = colb & 7;
          #pragma unroll
          for (int r = 0; r < 4; r++) {
            int rr = mi * 16 + lg * 4 + r;
            Pw[rr * 64 + ((gcol ^ (rr & 7)) * 8) + crem] = bf16_rn(sf[mi][ci][r]);
          }
        }

      // O += P (Vh + Vl)
      bf16x8 pa[2][2];
      #pragma unroll
      for (int mi = 0; mi < 2; mi++)
        #pragma unroll
        for (int ks = 0; ks < 2; ks++)
          pa[mi][ks] = *(const bf16x8*)(Pw + offP[mi][ks]);
      __builtin_amdgcn_s_setprio(1);
      #pragma unroll
      for (int di = 0; di < 4; di++) {
        bf16x8 vh0 = *(const bf16x8*)(VHc + offK[di][0]);
        bf16x8 vh1 = *(const bf16x8*)(VHc + offK[di][1]);
        bf16x8 vl0 = *(const bf16x8*)(VLc + offK[di][0]);
        bf16x8 vl1 = *(const bf16x8*)(VLc + offK[di][1]);
        #pragma unroll
        for (int mi = 0; mi < 2; mi++) {
          f32x4 o = oacc[mi][di];
          o = __builtin_amdgcn_mfma_f32_16x16x32_bf16(pa[mi][0], vh0, o, 0, 0, 0);
          o = __builtin_amdgcn_mfma_f32_16x16x32_bf16(pa[mi][1], vh1, o, 0, 0, 0);
          o = __builtin_amdgcn_mfma_f32_16x16x32_bf16(pa[mi][0], vl0, o, 0, 0, 0);
          o = __builtin_amdgcn_mfma_f32_16x16x32_bf16(pa[mi][1], vl1, o, 0, 0, 0);
          oacc[mi][di] = o;
        }
      }
      __builtin_amdgcn_s_setprio(0);
    }
    __syncthreads();   // drains vmcnt: next buffer ready; cur buffer reusable
  }

  // epilogue: normalize, write split-bf16 att [B*S][1024]
  #pragma unroll
  for (int mi = 0; mi < 2; mi++) {
    float inv[4];
    #pragma unroll
    for (int r = 0; r < 4; r++) inv[r] = 1.f / l_[mi][r];
    #pragma unroll
    for (int di = 0; di < 4; di++) {
      f32x4 o = oacc[mi][di];
      #pragma unroll
      for (int r = 0; r < 4; r++) {
        float v = o[r] * inv[r];
        int srow = q0w + mi * 16 + lg * 4 + r;
        size_t idx = ((size_t)b * Ss + srow) * 1024 + h * 64 + di * 16 + lrow;
        unsigned short hi = bf16_rn(v);
        atthi[idx] = hi;
        attlo[idx] = bf16_rn(v - bf16_f(hi));
      }
    }
  }
}

// ---------------------------------------------------------------------------
extern "C" void kernel_launch(void* const* d_in, const int* in_sizes, int n_in,
                              void* d_out, int out_size, void* d_ws, size_t ws_size,
                              hipStream_t stream) {
  const float* x    = (const float*)d_in[0];
  // d_in[1] = causal mask (hardcoded)
  const float* Wqkv = (const float*)d_in[2];
  const float* bqkv = (const float*)d_in[3];
  const float* Wout = (const float*)d_in[4];
  const float* bout = (const float*)d_in[5];
  float* out = (float*)d_out;

  char* ws = (char*)d_ws;
  unsigned short* Qh  = (unsigned short*)(ws);
  unsigned short* Ql  = (unsigned short*)(ws + 8388608);
  unsigned short* Kh  = (unsigned short*)(ws + 16777216);
  unsigned short* Kl  = (unsigned short*)(ws + 25165824);
  unsigned short* Vth = (unsigned short*)(ws + 33554432);
  unsigned short* Vtl = (unsigned short*)(ws + 41943040);
  unsigned short* atthi = (unsigned short*)(ws + 50331648);
  unsigned short* attlo = (unsigned short*)(ws + 58720256);
  unsigned short* xhi = (unsigned short*)(ws + 67108864);
  unsigned short* xlo = (unsigned short*)(ws + 75497472);
  unsigned short* wqh = (unsigned short*)(ws + 83886080);
  unsigned short* wql = (unsigned short*)(ws + 90177536);
  unsigned short* woh = (unsigned short*)(ws + 96468992);
  unsigned short* wol = (unsigned short*)(ws + 98566144);

  const int M = Bb * Ss;  // 4096

  split_f32<<<(M * Dd / 8) / 256, 256, 0, stream>>>(x, xhi, xlo, M * Dd / 8);
  transpose_split_f32<<<dim3(3 * Dd / 32, Dd / 32), 256, 0, stream>>>(Wqkv, wqh, wql, Dd, 3 * Dd);
  transpose_split_f32<<<dim3(Dd / 32, Dd / 32), 256, 0, stream>>>(Wout, woh, wol, Dd, Dd);

  // 1) QKV projection, fused split + per-head scatter (Q log2-scaled, Vt transposed)
  gemm_qkv<1024><<<dim3(3 * Dd / 128, M / 128), 256, 0, stream>>>(
      xhi, xlo, wqh, wql, bqkv, Qh, Ql, Kh, Kl, Vth, Vtl);

  // 2) MFMA causal flash attention (balanced pairing, 8 waves) -> split-bf16 att
  flash_attn_mfma<<<dim3(Ss / 256, Hh, Bb), 512, 0, stream>>>(
      Qh, Ql, Kh, Kl, Vth, Vtl, atthi, attlo);

  // 3) output projection
  gemm_split_bf16<1024><<<dim3(Dd / 128, M / 128), 256, 0, stream>>>(
      atthi, attlo, woh, wol, bout, out, Dd);
}

// Round 8
// 312.299 us; speedup vs baseline: 3.1719x; 1.1384x over previous
//
#include <hip/hip_runtime.h>
#include <math.h>

// Problem constants
constexpr int Bb = 2, Ss = 2048, Dd = 1024, Hh = 16, HDd = 64;

typedef __attribute__((ext_vector_type(8))) short bf16x8;     // MFMA A/B frag
typedef __attribute__((ext_vector_type(4))) float f32x4;      // MFMA C/D frag
typedef __attribute__((ext_vector_type(8))) unsigned short u16x8;
typedef __attribute__((ext_vector_type(4))) unsigned short u16x4;

__device__ __forceinline__ unsigned short bf16_rn(float f) {
  unsigned int u = __float_as_uint(f);
  u += 0x7fffu + ((u >> 16) & 1u);
  return (unsigned short)(u >> 16);
}
__device__ __forceinline__ float bf16_f(unsigned short h) {
  return __uint_as_float(((unsigned int)h) << 16);
}

// ---------------------------------------------------------------------------
// split fp32 array into hi/lo bf16 arrays
// ---------------------------------------------------------------------------
__global__ __launch_bounds__(256) void split_f32(
    const float* __restrict__ in, unsigned short* __restrict__ hi,
    unsigned short* __restrict__ lo, int n8) {
  int i = blockIdx.x * 256 + threadIdx.x;
  if (i >= n8) return;
  const float4* p = (const float4*)in + (size_t)i * 2;
  float4 a = p[0], b = p[1];
  float v[8] = {a.x, a.y, a.z, a.w, b.x, b.y, b.z, b.w};
  u16x8 h, l;
  #pragma unroll
  for (int j = 0; j < 8; j++) {
    unsigned short hb = bf16_rn(v[j]);
    h[j] = hb;
    l[j] = bf16_rn(v[j] - bf16_f(hb));
  }
  *(u16x8*)(hi + (size_t)i * 8) = h;
  *(u16x8*)(lo + (size_t)i * 8) = l;
}

// transpose W[K][N] -> Wt[N][K], split into hi/lo bf16
__global__ __launch_bounds__(256) void transpose_split_f32(
    const float* __restrict__ W, unsigned short* __restrict__ Thi,
    unsigned short* __restrict__ Tlo, int K, int N) {
  __shared__ float tile[32][33];
  int n0 = blockIdx.x * 32, k0 = blockIdx.y * 32;
  int t = threadIdx.x;
  #pragma unroll
  for (int p = 0; p < 4; p++) {
    int idx = t + p * 256;
    int kk = idx >> 5, nn = idx & 31;
    tile[kk][nn] = W[(size_t)(k0 + kk) * N + n0 + nn];
  }
  __syncthreads();
  #pragma unroll
  for (int p = 0; p < 4; p++) {
    int idx = t + p * 256;
    int nn = idx >> 5, kk = idx & 31;
    float v = tile[kk][nn];
    unsigned short hb = bf16_rn(v);
    size_t o = (size_t)(n0 + nn) * K + k0 + kk;
    Thi[o] = hb;
    Tlo[o] = bf16_rn(v - bf16_f(hb));
  }
}

// ---------------------------------------------------------------------------
typedef __attribute__((address_space(3))) unsigned int lds_u32;
typedef const __attribute__((address_space(1))) unsigned int glb_u32;
__device__ __forceinline__ void gload16(const void* g, void* l) {
  __builtin_amdgcn_global_load_lds((glb_u32*)g, (lds_u32*)l, 16, 0, 0);
}

// raw barrier with compiler memory fences (no vmcnt drain)
__device__ __forceinline__ void syncb() {
  asm volatile("" ::: "memory");
  __builtin_amdgcn_s_barrier();
  asm volatile("" ::: "memory");
}
template<int N> __device__ __forceinline__ void wait_vmcnt() {
  if constexpr (N == 0)      asm volatile("s_waitcnt vmcnt(0)" ::: "memory");
  else if constexpr (N == 4) asm volatile("s_waitcnt vmcnt(4)" ::: "memory");
  else if constexpr (N == 7) asm volatile("s_waitcnt vmcnt(7)" ::: "memory");
}

// ---------------------------------------------------------------------------
// 8-wave counted-vmcnt split-bf16 GEMM core (T3+T4).
// A row-major hi/lo [M][KD]; B transposed hi/lo [N][KD].
// 512 threads, waves 2x4 (wave output BM/2 x BN/4). BK=32, 2 LDS buffers,
// STAGE(t+2) issued after post-read barrier; vmcnt(NA+NB) counted, never 0
// in steady state. Swizzle: same XOR-granule involution as verified m97 core
// (pre-swizzled global src, linear LDS dest, swizzled ds_read).
// ---------------------------------------------------------------------------
template<int BM, int BN>
__device__ __forceinline__ void gemm_core256(
    const unsigned short* __restrict__ Ahi, const unsigned short* __restrict__ Alo,
    const unsigned short* __restrict__ Bhi, const unsigned short* __restrict__ Blo,
    int KD, f32x4 (&acc)[BM / 32][BN / 64])
{
  constexpr int MF = BM / 32, NF = BN / 64;       // frag counts per wave
  constexpr int NA = BM / 64, NB = BN / 64;       // gloads per thread per tile
  constexpr int NV = NA + NB;
  constexpr int AELT = 2 * BM * 32;               // ushorts in A region (hi+lo)
  constexpr int BELT = 2 * BN * 32;
  constexpr int ALO = BM * 32, BLO = BN * 32;     // hi->lo read offsets
  __shared__ unsigned short lds[2][AELT + BELT];

  const int tid = threadIdx.x, lane = tid & 63, wid = tid >> 6;
  const int m0 = blockIdx.y * BM, n0 = blockIdx.x * BN;
  const int wrow = wid >> 2, wcol = wid & 3;
  const int lrow = lane & 15, g = lane >> 4;

  // staging: pre-swizzled global sources, wave-uniform linear LDS dests
  const unsigned short* srcA[NA]; int dstA[NA];
  #pragma unroll
  for (int i = 0; i < NA; i++) {
    int gi = tid + i * 512;
    int lr = gi >> 2, s = gi & 3, gs = s ^ ((lr >> 1) & 3);
    const unsigned short* bp = (lr < BM) ? Ahi : Alo;
    int row = (lr < BM) ? lr : lr - BM;
    srcA[i] = bp + (size_t)(m0 + row) * KD + gs * 8;
    dstA[i] = (gi & ~63) * 8;
  }
  const unsigned short* srcB[NB]; int dstB[NB];
  #pragma unroll
  for (int i = 0; i < NB; i++) {
    int gi = tid + i * 512;
    int lr = gi >> 2, s = gi & 3, gs = s ^ ((lr >> 1) & 3);
    const unsigned short* bp = (lr < BN) ? Bhi : Blo;
    int row = (lr < BN) ? lr : lr - BN;
    srcB[i] = bp + (size_t)(n0 + row) * KD + gs * 8;
    dstB[i] = AELT + (gi & ~63) * 8;
  }

  // fragment ds_read offsets (swizzled; constant across K)
  int offA[MF], offB[NF];
  #pragma unroll
  for (int m = 0; m < MF; m++) {
    int row = wrow * (BM / 2) + m * 16 + lrow;
    offA[m] = row * 32 + ((g ^ ((row >> 1) & 3)) * 8);
  }
  #pragma unroll
  for (int n = 0; n < NF; n++) {
    int row = wcol * (BN / 4) + n * 16 + lrow;
    offB[n] = AELT + row * 32 + ((g ^ ((row >> 1) & 3)) * 8);
  }

  #pragma unroll
  for (int m = 0; m < MF; m++)
    #pragma unroll
    for (int n = 0; n < NF; n++) acc[m][n] = (f32x4){0.f, 0.f, 0.f, 0.f};

  const int nk = KD / 32;

  // prologue: stage tiles 0 and 1
  #pragma unroll
  for (int i = 0; i < NA; i++) gload16(srcA[i], &lds[0][dstA[i]]);
  #pragma unroll
  for (int i = 0; i < NB; i++) gload16(srcB[i], &lds[0][dstB[i]]);
  #pragma unroll
  for (int i = 0; i < NA; i++) gload16(srcA[i] + 32, &lds[1][dstA[i]]);
  #pragma unroll
  for (int i = 0; i < NB; i++) gload16(srcB[i] + 32, &lds[1][dstB[i]]);
  wait_vmcnt<NV>();   // tile 0 resident (tile 1 still in flight)
  syncb();

  for (int t = 0; t < nk; ++t) {
    const unsigned short* L = lds[t & 1];

    bf16x8 bh[NF], bl[NF];
    #pragma unroll
    for (int n = 0; n < NF; n++) {
      bh[n] = *(const bf16x8*)(L + offB[n]);
      bl[n] = *(const bf16x8*)(L + offB[n] + BLO);
    }
    // phase 0: first half of m-frags
    {
      bf16x8 ah[MF / 2], al[MF / 2];
      #pragma unroll
      for (int m = 0; m < MF / 2; m++) {
        ah[m] = *(const bf16x8*)(L + offA[m]);
        al[m] = *(const bf16x8*)(L + offA[m] + ALO);
      }
      __builtin_amdgcn_s_setprio(1);
      #pragma unroll
      for (int m = 0; m < MF / 2; m++)
        #pragma unroll
        for (int n = 0; n < NF; n++) {
          acc[m][n] = __builtin_amdgcn_mfma_f32_16x16x32_bf16(ah[m], bh[n], acc[m][n], 0, 0, 0);
          acc[m][n] = __builtin_amdgcn_mfma_f32_16x16x32_bf16(ah[m], bl[n], acc[m][n], 0, 0, 0);
          acc[m][n] = __builtin_amdgcn_mfma_f32_16x16x32_bf16(al[m], bh[n], acc[m][n], 0, 0, 0);
        }
      __builtin_amdgcn_s_setprio(0);
    }
    syncb();   // mid-tile lockstep
    // phase 1: second half of m-frags (B frags reused from regs)
    {
      bf16x8 ah[MF / 2], al[MF / 2];
      #pragma unroll
      for (int m = 0; m < MF / 2; m++) {
        ah[m] = *(const bf16x8*)(L + offA[m + MF / 2]);
        al[m] = *(const bf16x8*)(L + offA[m + MF / 2] + ALO);
      }
      __builtin_amdgcn_s_setprio(1);
      #pragma unroll
      for (int m = 0; m < MF / 2; m++)
        #pragma unroll
        for (int n = 0; n < NF; n++) {
          acc[m + MF / 2][n] = __builtin_amdgcn_mfma_f32_16x16x32_bf16(ah[m], bh[n], acc[m + MF / 2][n], 0, 0, 0);
          acc[m + MF / 2][n] = __builtin_amdgcn_mfma_f32_16x16x32_bf16(ah[m], bl[n], acc[m + MF / 2][n], 0, 0, 0);
          acc[m + MF / 2][n] = __builtin_amdgcn_mfma_f32_16x16x32_bf16(al[m], bh[n], acc[m + MF / 2][n], 0, 0, 0);
        }
      __builtin_amdgcn_s_setprio(0);
    }

    if (t + 1 < nk) {
      asm volatile("s_waitcnt lgkmcnt(0)" ::: "memory");  // all my reads landed
      syncb();          // ALL waves done reading buf (t&1) -> safe to overwrite
      if (t + 2 < nk) {
        const int koff = (t + 2) * 32;
        unsigned short* W = lds[t & 1];
        #pragma unroll
        for (int i = 0; i < NA; i++) gload16(srcA[i] + koff, W + dstA[i]);
        #pragma unroll
        for (int i = 0; i < NB; i++) gload16(srcB[i] + koff, W + dstB[i]);
        wait_vmcnt<NV>();   // counted: tile t+1 resident, t+2 in flight
      } else {
        wait_vmcnt<0>();    // tail: drain
      }
      syncb();              // next buffer ready for all waves
    }
  }
}

// QKV GEMM (BM=256,BN=192): scatter epilogue -> per-head split-bf16 Q/K/Vt.
// Q pre-scaled by (1/sqrt(HD)) * log2(e) for exp2-domain softmax.
__global__ __launch_bounds__(512) void gemm_qkv256(
    const unsigned short* __restrict__ Ahi, const unsigned short* __restrict__ Alo,
    const unsigned short* __restrict__ Bhi, const unsigned short* __restrict__ Blo,
    const float* __restrict__ bias,
    unsigned short* __restrict__ Qh, unsigned short* __restrict__ Ql,
    unsigned short* __restrict__ Kh, unsigned short* __restrict__ Kl,
    unsigned short* __restrict__ Vth, unsigned short* __restrict__ Vtl)
{
  f32x4 acc[8][3];
  gemm_core256<256, 192>(Ahi, Alo, Bhi, Blo, 1024, acc);

  const int tid = threadIdx.x, lane = tid & 63, wid = tid >> 6;
  const int lrow = lane & 15, g = lane >> 4;
  const int m0 = blockIdx.y * 256, n0 = blockIdx.x * 192;
  const int wrow = wid >> 2, wcol = wid & 3;
  const int bidx = m0 >> 11;
  const int sbase = (m0 & 2047) + wrow * 128 + g * 4;
  #pragma unroll
  for (int n = 0; n < 3; n++) {
    int gcol = n0 + wcol * 48 + n * 16 + lrow;
    unsigned hh = (unsigned)gcol / 192u;
    int inner = gcol - (int)hh * 192;
    int part = inner >> 6;
    int d = inner & 63;
    float bv = bias[gcol];
    size_t base = (size_t)(bidx * 16 + (int)hh) * 131072;
    #pragma unroll
    for (int m = 0; m < 8; m++) {
      f32x4 a = acc[m][n];
      int s0 = sbase + m * 16;
      if (part == 0) {
        #pragma unroll
        for (int r = 0; r < 4; r++) {
          float v = (a[r] + bv) * 0.18033688011112042f;  // 0.125 * log2(e)
          unsigned short hi = bf16_rn(v);
          size_t ix = base + (size_t)(s0 + r) * 64 + d;
          Qh[ix] = hi; Ql[ix] = bf16_rn(v - bf16_f(hi));
        }
      } else if (part == 1) {
        #pragma unroll
        for (int r = 0; r < 4; r++) {
          float v = a[r] + bv;
          unsigned short hi = bf16_rn(v);
          size_t ix = base + (size_t)(s0 + r) * 64 + d;
          Kh[ix] = hi; Kl[ix] = bf16_rn(v - bf16_f(hi));
        }
      } else {
        u16x4 hv, lv;
        #pragma unroll
        for (int r = 0; r < 4; r++) {
          float v = a[r] + bv;
          hv[r] = bf16_rn(v);
          lv[r] = bf16_rn(v - bf16_f(hv[r]));
        }
        size_t ix = base + (size_t)d * 2048 + s0;
        *(u16x4*)(Vth + ix) = hv;
        *(u16x4*)(Vtl + ix) = lv;
      }
    }
  }
}

// Out-projection GEMM (BM=BN=128): plain f32 + bias epilogue.
__global__ __launch_bounds__(512) void gemm_out256(
    const unsigned short* __restrict__ Ahi, const unsigned short* __restrict__ Alo,
    const unsigned short* __restrict__ Bhi, const unsigned short* __restrict__ Blo,
    const float* __restrict__ bias, float* __restrict__ C)
{
  f32x4 acc[4][2];
  gemm_core256<128, 128>(Ahi, Alo, Bhi, Blo, 1024, acc);

  const int tid = threadIdx.x, lane = tid & 63, wid = tid >> 6;
  const int lrow = lane & 15, g = lane >> 4;
  const int m0 = blockIdx.y * 128, n0 = blockIdx.x * 128;
  const int wrow = wid >> 2, wcol = wid & 3;
  #pragma unroll
  for (int n = 0; n < 2; n++) {
    int gcol = n0 + wcol * 32 + n * 16 + lrow;
    float bv = bias[gcol];
    #pragma unroll
    for (int m = 0; m < 4; m++) {
      f32x4 a = acc[m][n];
      #pragma unroll
      for (int r = 0; r < 4; r++) {
        int grow = m0 + wrow * 64 + m * 16 + g * 4 + r;
        C[(size_t)grow * 1024 + gcol] = a[r] + bv;
      }
    }
  }
}

// ---------------------------------------------------------------------------
// MFMA flash attention (round-5, unchanged): causal-balanced pairing,
// 8 waves x 32 rows, 2-phase dbuf, exp2-domain softmax.
// ---------------------------------------------------------------------------
__global__ __launch_bounds__(512) void flash_attn_mfma(
    const unsigned short* __restrict__ Qh, const unsigned short* __restrict__ Ql,
    const unsigned short* __restrict__ Kh, const unsigned short* __restrict__ Kl,
    const unsigned short* __restrict__ Vth, const unsigned short* __restrict__ Vtl,
    unsigned short* __restrict__ atthi, unsigned short* __restrict__ attlo)
{
  const int pidx = blockIdx.x;
  const int h = blockIdx.y, b = blockIdx.z;
  const int bh = b * Hh + h;
  const int NT = Ss / 128;
  const int qtA = pidx, qtB = NT - 1 - pidx;
  const int tid = threadIdx.x, lane = tid & 63, wid = tid >> 6;
  const int q0w = (wid < 4) ? (qtA * 128 + wid * 32)
                            : (qtB * 128 + (wid - 4) * 32);
  const int lrow = lane & 15, lg = lane >> 4;

  __shared__ unsigned short KH[2][4096], KL[2][4096], VH[2][4096], VL[2][4096];
  __shared__ unsigned short Pbuf[8][2048];

  const size_t hb = (size_t)bh * 131072;
  const unsigned short* qhb = Qh + hb;
  const unsigned short* qlb = Ql + hb;
  const unsigned short* khb = Kh + hb;
  const unsigned short* klb = Kl + hb;
  const unsigned short* vhb = Vth + hb;
  const unsigned short* vlb = Vtl + hb;

  bf16x8 qfh[2][2], qfl[2][2];
  #pragma unroll
  for (int mi = 0; mi < 2; mi++)
    #pragma unroll
    for (int ks = 0; ks < 2; ks++) {
      int off = (q0w + mi * 16 + lrow) * 64 + ks * 32 + lg * 8;
      qfh[mi][ks] = *(const bf16x8*)(qhb + off);
      qfl[mi][ks] = *(const bf16x8*)(qlb + off);
    }

  int offK[4][2], offP[2][2];
  #pragma unroll
  for (int ci = 0; ci < 4; ci++)
    #pragma unroll
    for (int ks = 0; ks < 2; ks++) {
      int row = ci * 16 + lrow;
      offK[ci][ks] = row * 64 + (((ks * 4 + lg) ^ (row & 7)) * 8);
    }
  #pragma unroll
  for (int mi = 0; mi < 2; mi++)
    #pragma unroll
    for (int ks = 0; ks < 2; ks++) {
      int row = mi * 16 + lrow;
      offP[mi][ks] = row * 64 + (((ks * 4 + lg) ^ (row & 7)) * 8);
    }

  const int sr = tid >> 3, sg = ((tid & 7) ^ ((tid >> 3) & 7)) * 8;

  float m_[2][4], l_[2][4];
  f32x4 oacc[2][4];
  #pragma unroll
  for (int mi = 0; mi < 2; mi++)
    #pragma unroll
    for (int r = 0; r < 4; r++) { m_[mi][r] = -INFINITY; l_[mi][r] = 0.f; }
  #pragma unroll
  for (int mi = 0; mi < 2; mi++)
    #pragma unroll
    for (int di = 0; di < 4; di++) oacc[mi][di] = (f32x4){0.f, 0.f, 0.f, 0.f};

  unsigned short* Pw = Pbuf[wid];
  const int nt = 2 * (qtB + 1);

  gload16(khb + (size_t)sr * 64 + sg, KH[0] + wid * 512);
  gload16(klb + (size_t)sr * 64 + sg, KL[0] + wid * 512);
  gload16(vhb + (size_t)sr * 2048 + sg, VH[0] + wid * 512);
  gload16(vlb + (size_t)sr * 2048 + sg, VL[0] + wid * 512);
  __syncthreads();

  for (int t = 0; t < nt; ++t) {
    const int kv0 = t * 64;
    if (t + 1 < nt) {
      const int nb = (t + 1) & 1;
      const int nk = kv0 + 64;
      gload16(khb + (size_t)(nk + sr) * 64 + sg, KH[nb] + wid * 512);
      gload16(klb + (size_t)(nk + sr) * 64 + sg, KL[nb] + wid * 512);
      gload16(vhb + (size_t)sr * 2048 + nk + sg, VH[nb] + wid * 512);
      gload16(vlb + (size_t)sr * 2048 + nk + sg, VL[nb] + wid * 512);
    }

    if (kv0 <= q0w + 31) {
      const int cb = t & 1;
      const unsigned short* KHc = KH[cb];
      const unsigned short* KLc = KL[cb];
      const unsigned short* VHc = VH[cb];
      const unsigned short* VLc = VL[cb];

      f32x4 sf[2][4];
      #pragma unroll
      for (int mi = 0; mi < 2; mi++)
        #pragma unroll
        for (int ci = 0; ci < 4; ci++) sf[mi][ci] = (f32x4){0.f, 0.f, 0.f, 0.f};
      __builtin_amdgcn_s_setprio(1);
      #pragma unroll
      for (int ci = 0; ci < 4; ci++) {
        bf16x8 kh0 = *(const bf16x8*)(KHc + offK[ci][0]);
        bf16x8 kh1 = *(const bf16x8*)(KHc + offK[ci][1]);
        bf16x8 kl0 = *(const bf16x8*)(KLc + offK[ci][0]);
        bf16x8 kl1 = *(const bf16x8*)(KLc + offK[ci][1]);
        #pragma unroll
        for (int mi = 0; mi < 2; mi++) {
          f32x4 s = sf[mi][ci];
          s = __builtin_amdgcn_mfma_f32_16x16x32_bf16(qfh[mi][0], kh0, s, 0, 0, 0);
          s = __builtin_amdgcn_mfma_f32_16x16x32_bf16(qfh[mi][1], kh1, s, 0, 0, 0);
          s = __builtin_amdgcn_mfma_f32_16x16x32_bf16(qfh[mi][0], kl0, s, 0, 0, 0);
          s = __builtin_amdgcn_mfma_f32_16x16x32_bf16(qfh[mi][1], kl1, s, 0, 0, 0);
          s = __builtin_amdgcn_mfma_f32_16x16x32_bf16(qfl[mi][0], kh0, s, 0, 0, 0);
          s = __builtin_amdgcn_mfma_f32_16x16x32_bf16(qfl[mi][1], kh1, s, 0, 0, 0);
          sf[mi][ci] = s;
        }
      }
      __builtin_amdgcn_s_setprio(0);

      if (kv0 + 63 > q0w) {
        #pragma unroll
        for (int mi = 0; mi < 2; mi++)
          #pragma unroll
          for (int ci = 0; ci < 4; ci++)
            #pragma unroll
            for (int r = 0; r < 4; r++) {
              int q = q0w + mi * 16 + lg * 4 + r;
              int kv = kv0 + ci * 16 + lrow;
              if (kv > q) sf[mi][ci][r] = -1e30f;
            }
      }

      #pragma unroll
      for (int mi = 0; mi < 2; mi++)
        #pragma unroll
        for (int r = 0; r < 4; r++) {
          float mx = fmaxf(fmaxf(sf[mi][0][r], sf[mi][1][r]),
                           fmaxf(sf[mi][2][r], sf[mi][3][r]));
          mx = fmaxf(mx, __shfl_xor(mx, 1));
          mx = fmaxf(mx, __shfl_xor(mx, 2));
          mx = fmaxf(mx, __shfl_xor(mx, 4));
          mx = fmaxf(mx, __shfl_xor(mx, 8));
          float mn = fmaxf(m_[mi][r], mx);
          float alpha = __builtin_amdgcn_exp2f(m_[mi][r] - mn);
          m_[mi][r] = mn;
          float rs = 0.f;
          #pragma unroll
          for (int ci = 0; ci < 4; ci++) {
            float p = __builtin_amdgcn_exp2f(sf[mi][ci][r] - mn);
            sf[mi][ci][r] = p;
            rs += p;
          }
          rs += __shfl_xor(rs, 1);
          rs += __shfl_xor(rs, 2);
          rs += __shfl_xor(rs, 4);
          rs += __shfl_xor(rs, 8);
          l_[mi][r] = l_[mi][r] * alpha + rs;
          #pragma unroll
          for (int di = 0; di < 4; di++) oacc[mi][di][r] *= alpha;
        }

      #pragma unroll
      for (int mi = 0; mi < 2; mi++)
        #pragma unroll
        for (int ci = 0; ci < 4; ci++) {
          int colb = ci * 16 + lrow;
          int gcol = colb >> 3, crem = colb & 7;
          #pragma unroll
          for (int r = 0; r < 4; r++) {
            int rr = mi * 16 + lg * 4 + r;
            Pw[rr * 64 + ((gcol ^ (rr & 7)) * 8) + crem] = bf16_rn(sf[mi][ci][r]);
          }
        }

      bf16x8 pa[2][2];
      #pragma unroll
      for (int mi = 0; mi < 2; mi++)
        #pragma unroll
        for (int ks = 0; ks < 2; ks++)
          pa[mi][ks] = *(const bf16x8*)(Pw + offP[mi][ks]);
      __builtin_amdgcn_s_setprio(1);
      #pragma unroll
      for (int di = 0; di < 4; di++) {
        bf16x8 vh0 = *(const bf16x8*)(VHc + offK[di][0]);
        bf16x8 vh1 = *(const bf16x8*)(VHc + offK[di][1]);
        bf16x8 vl0 = *(const bf16x8*)(VLc + offK[di][0]);
        bf16x8 vl1 = *(const bf16x8*)(VLc + offK[di][1]);
        #pragma unroll
        for (int mi = 0; mi < 2; mi++) {
          f32x4 o = oacc[mi][di];
          o = __builtin_amdgcn_mfma_f32_16x16x32_bf16(pa[mi][0], vh0, o, 0, 0, 0);
          o = __builtin_amdgcn_mfma_f32_16x16x32_bf16(pa[mi][1], vh1, o, 0, 0, 0);
          o = __builtin_amdgcn_mfma_f32_16x16x32_bf16(pa[mi][0], vl0, o, 0, 0, 0);
          o = __builtin_amdgcn_mfma_f32_16x16x32_bf16(pa[mi][1], vl1, o, 0, 0, 0);
          oacc[mi][di] = o;
        }
      }
      __builtin_amdgcn_s_setprio(0);
    }
    __syncthreads();
  }

  #pragma unroll
  for (int mi = 0; mi < 2; mi++) {
    float inv[4];
    #pragma unroll
    for (int r = 0; r < 4; r++) inv[r] = 1.f / l_[mi][r];
    #pragma unroll
    for (int di = 0; di < 4; di++) {
      f32x4 o = oacc[mi][di];
      #pragma unroll
      for (int r = 0; r < 4; r++) {
        float v = o[r] * inv[r];
        int srow = q0w + mi * 16 + lg * 4 + r;
        size_t idx = ((size_t)b * Ss + srow) * 1024 + h * 64 + di * 16 + lrow;
        unsigned short hi = bf16_rn(v);
        atthi[idx] = hi;
        attlo[idx] = bf16_rn(v - bf16_f(hi));
      }
    }
  }
}

// ---------------------------------------------------------------------------
extern "C" void kernel_launch(void* const* d_in, const int* in_sizes, int n_in,
                              void* d_out, int out_size, void* d_ws, size_t ws_size,
                              hipStream_t stream) {
  const float* x    = (const float*)d_in[0];
  // d_in[1] = causal mask (hardcoded)
  const float* Wqkv = (const float*)d_in[2];
  const float* bqkv = (const float*)d_in[3];
  const float* Wout = (const float*)d_in[4];
  const float* bout = (const float*)d_in[5];
  float* out = (float*)d_out;

  char* ws = (char*)d_ws;
  unsigned short* Qh  = (unsigned short*)(ws);
  unsigned short* Ql  = (unsigned short*)(ws + 8388608);
  unsigned short* Kh  = (unsigned short*)(ws + 16777216);
  unsigned short* Kl  = (unsigned short*)(ws + 25165824);
  unsigned short* Vth = (unsigned short*)(ws + 33554432);
  unsigned short* Vtl = (unsigned short*)(ws + 41943040);
  unsigned short* atthi = (unsigned short*)(ws + 50331648);
  unsigned short* attlo = (unsigned short*)(ws + 58720256);
  unsigned short* xhi = (unsigned short*)(ws + 67108864);
  unsigned short* xlo = (unsigned short*)(ws + 75497472);
  unsigned short* wqh = (unsigned short*)(ws + 83886080);
  unsigned short* wql = (unsigned short*)(ws + 90177536);
  unsigned short* woh = (unsigned short*)(ws + 96468992);
  unsigned short* wol = (unsigned short*)(ws + 98566144);

  const int M = Bb * Ss;  // 4096

  split_f32<<<(M * Dd / 8) / 256, 256, 0, stream>>>(x, xhi, xlo, M * Dd / 8);
  transpose_split_f32<<<dim3(3 * Dd / 32, Dd / 32), 256, 0, stream>>>(Wqkv, wqh, wql, Dd, 3 * Dd);
  transpose_split_f32<<<dim3(Dd / 32, Dd / 32), 256, 0, stream>>>(Wout, woh, wol, Dd, Dd);

  // 1) QKV projection: 256x192 tile, counted-vmcnt pipeline, scatter epilogue
  gemm_qkv256<<<dim3(16, 16), 512, 0, stream>>>(
      xhi, xlo, wqh, wql, bqkv, Qh, Ql, Kh, Kl, Vth, Vtl);

  // 2) MFMA causal flash attention (balanced pairing, 8 waves)
  flash_attn_mfma<<<dim3(Ss / 256, Hh, Bb), 512, 0, stream>>>(
      Qh, Ql, Kh, Kl, Vth, Vtl, atthi, attlo);

  // 3) output projection: 128x128 tile, 8 waves, counted-vmcnt pipeline
  gemm_out256<<<dim3(8, 32), 512, 0, stream>>>(
      atthi, attlo, woh, wol, bout, out);
}